// Round 1
// baseline (641.706 us; speedup 1.0000x reference)
//
#include <hip/hip_runtime.h>
#include <hip/hip_bf16.h>

// N=8192, D=512.  Q = emb@Wqk^T+bqk (K==Q); out = softmax(QK^T/sqrt(512)) @ V.
// Softmax rows sum to 1 => out = (softmax(S)@emb) @ Wv^T + bv (V never built).
// R15: attn64 (284us) was NOT at a HW roofline (L2 path at 21% of 34.5 TB/s
// ceiling; MfmaUtil 20%). New attn128: Tq=128 (halves L1/L2 traffic 2.05->1.05GB)
// via inverted placement: Q-fragments in registers (8 waves x 16 rows), K-tile
// double-buffered in LDS via swizzled-source global_load_lds, P single 16KB
// XOR-swizzled buffer. Counted-vmcnt style prefetch (K(t+1) issued at iter top,
// only drained by end-of-iter syncthreads after a full compute phase).
// Needs ~49.1MB ws; old R13/R14 paths kept as fallbacks.

#define NTOK 8192
#define DIM  512

typedef unsigned short ushort_t;
typedef unsigned int u32;
typedef __attribute__((ext_vector_type(8))) __bf16 bf16x8;
typedef __attribute__((ext_vector_type(4))) float f32x4;

__device__ __forceinline__ float bf2f(ushort_t u) {
    union { unsigned int i; float f; } v; v.i = ((unsigned int)u) << 16; return v.f;
}
__device__ __forceinline__ ushort_t f2bf(float f) {
    union { float f; unsigned int i; } v; v.f = f;
    unsigned int b = v.i;
    return (ushort_t)((b + 0x7FFFu + ((b >> 16) & 1u)) >> 16);   // RNE
}
__device__ __forceinline__ __bf16 f2bfh(float f) {
    union { ushort_t u; __bf16 h; } c; c.u = f2bf(f); return c.h;
}
__device__ __forceinline__ f32x4 mfma16(bf16x8 a, bf16x8 b, f32x4 c) {
    return __builtin_amdgcn_mfma_f32_16x16x32_bf16(a, b, c, 0, 0, 0);
}
__device__ __forceinline__ bf16x8 load8(const void* p, size_t idx, bool f32) {
    if (f32) {
        const float* f = (const float*)p + idx;
        bf16x8 r;
        #pragma unroll
        for (int j = 0; j < 8; ++j) r[j] = f2bfh(f[j]);
        return r;
    }
    return *(const bf16x8*)((const ushort_t*)p + idx);
}
__device__ __forceinline__ float loadS(const void* p, size_t idx, bool f32) {
    return f32 ? ((const float*)p)[idx] : bf2f(((const ushort_t*)p)[idx]);
}
__device__ __forceinline__ void gload_lds16(const ushort_t* g, ushort_t* l) {
    __builtin_amdgcn_global_load_lds(
        (const __attribute__((address_space(1))) u32*)g,
        (__attribute__((address_space(3))) u32*)l, 16, 0, 0);
}

#define LDA 520   // 260 dw, %32=4: uniform 2 dw/bank for b128 row reads
#define LDP 264

// ---------------------------------------------------------------------------
// Dtype probe: flag=1 => bf16 data, flag=0 => fp32.
// ---------------------------------------------------------------------------
__global__ void detect_kernel(const ushort_t* __restrict__ emb, int* __restrict__ flag)
{
    int lane = threadIdx.x;
    int cnt = 0;
    #pragma unroll
    for (int i = 0; i < 8; ++i) {
        ushort_t u = emb[(size_t)(lane * 8 + i) * 2];
        int a = u & 0x7FFF;
        int e = (u >> 7) & 0xFF;
        if (a == 0 || (e >= 111 && e <= 143)) cnt++;
    }
    cnt += __shfl_xor(cnt, 1);  cnt += __shfl_xor(cnt, 2);  cnt += __shfl_xor(cnt, 4);
    cnt += __shfl_xor(cnt, 8);  cnt += __shfl_xor(cnt, 16); cnt += __shfl_xor(cnt, 32);
    if (lane == 0) *flag = (cnt >= 460) ? 1 : 0;
}

// ---------------------------------------------------------------------------
// Prep: convert Wqk, Wv (512x512) + bqk, bv (512) to bf16 in ws.
// ---------------------------------------------------------------------------
__global__ __launch_bounds__(256)
void prep_kernel(const int* __restrict__ flag,
                 const void* __restrict__ Wqk, const void* __restrict__ bqk,
                 const void* __restrict__ Wv,  const void* __restrict__ bv,
                 ushort_t* __restrict__ Wqkb, ushort_t* __restrict__ bqkb,
                 ushort_t* __restrict__ Wvb,  ushort_t* __restrict__ bvb)
{
    const bool f32 = (*flag == 0);
    size_t gid = (size_t)blockIdx.x * 256 + threadIdx.x;   // 32768 threads
    size_t base = gid * 8;                                  // 262144 = 512*512
    *(bf16x8*)&Wqkb[base] = load8(Wqk, base, f32);
    *(bf16x8*)&Wvb[base]  = load8(Wv,  base, f32);
    if (gid < 64) {
        *(bf16x8*)&bqkb[base] = load8(bqk, base, f32);
        *(bf16x8*)&bvb[base]  = load8(bv,  base, f32);
    }
}

// ---------------------------------------------------------------------------
// Fused: Q[64 rows] = emb@Wqk^T+bqk AND embT columns, from one staged tile.
// ---------------------------------------------------------------------------
__global__ __launch_bounds__(512)
void projqT_kernel(const int* __restrict__ flag, const void* __restrict__ emb,
                   const ushort_t* __restrict__ Wb, const ushort_t* __restrict__ bb,
                   ushort_t* __restrict__ C, ushort_t* __restrict__ embT)
{
    __shared__ ushort_t Alds[64][LDA];   // 66,560 B
    const bool f32 = (*flag == 0);
    const int tid  = threadIdx.x;
    const int wave = tid >> 6;
    const int lane = tid & 63;
    const int quad = lane >> 4;
    const int col  = lane & 15;
    const int mblk = blockIdx.x * 64;

    #pragma unroll
    for (int i = 0; i < 8; ++i) {
        int chunk = i * 512 + tid;
        int row = chunk >> 6;
        int k8  = (chunk & 63) * 8;
        *(bf16x8*)&Alds[row][k8] = load8(emb, (size_t)(mblk + row) * 512 + k8, f32);
    }
    __syncthreads();

    // ---- transpose store: thread t owns dim t, 64 tokens (128 B) ----
    {
        ushort_t buf[64];
        #pragma unroll
        for (int r = 0; r < 64; ++r) buf[r] = Alds[r][tid];
        ushort_t* dst = embT + (size_t)tid * NTOK + mblk;
        #pragma unroll
        for (int i = 0; i < 8; ++i)
            *(uint4*)(dst + i * 8) = *(uint4*)&buf[i * 8];
    }

    // ---- Q projection (64 rows x this wave's 64 cols) ----
    f32x4 acc[4][4];
    #pragma unroll
    for (int r = 0; r < 4; ++r)
        #pragma unroll
        for (int c = 0; c < 4; ++c) acc[r][c] = (f32x4){0.f, 0.f, 0.f, 0.f};

    const int wcol = wave * 64;
    #pragma unroll
    for (int kk = 0; kk < 16; ++kk) {
        bf16x8 a[4];
        #pragma unroll
        for (int r = 0; r < 4; ++r)
            a[r] = *(const bf16x8*)&Alds[r * 16 + col][kk * 32 + quad * 8];
        #pragma unroll
        for (int c = 0; c < 4; ++c) {
            bf16x8 b = *(const bf16x8*)&Wb[(size_t)(wcol + c * 16 + col) * 512
                                           + kk * 32 + quad * 8];
            #pragma unroll
            for (int r = 0; r < 4; ++r)
                acc[r][c] = mfma16(a[r], b, acc[r][c]);
        }
    }

    #pragma unroll
    for (int r = 0; r < 4; ++r)
        #pragma unroll
        for (int c = 0; c < 4; ++c)
            #pragma unroll
            for (int g = 0; g < 4; ++g) {
                int m = mblk + r * 16 + quad * 4 + g;
                int n = wcol + c * 16 + col;
                C[(size_t)m * DIM + n] = f2bf(acc[r][c][g] + bf2f(bb[n]));
            }
}

// ---------------------------------------------------------------------------
// attn128 (R15): 256 blocks = 64 q-tiles (Tq=128) x 4 key-quarters, 512 thr
// (8 waves). Wave w holds Q rows [q0+16w, +16) as register A-fragments and
// owns output dims [64w, 64w+64). K-tile (64 keys) double-buffered in LDS,
// staged by global_load_lds with XOR-swizzled SOURCE (linear dest); reads
// apply the same XOR -> 2-way max (free). P: single 16KB swizzled buffer.
// ---------------------------------------------------------------------------
#define QT   128
#define KTI  64
#define NITR 32

__global__ __launch_bounds__(512, 2)
void attn128_kernel(const ushort_t* __restrict__ Q, const ushort_t* __restrict__ embT,
                    ushort_t* __restrict__ P, float* __restrict__ lsumA)
{
    __shared__ ushort_t Klds[2][KTI * DIM];   // 2 x 64 KB
    __shared__ ushort_t Plds[QT * KTI];       // 16 KB

    const int tid  = threadIdx.x;
    const int wave = tid >> 6;
    const int lane = tid & 63;
    const int quad = lane >> 4;
    const int col  = lane & 15;
    const int qt   = blockIdx.x & 63;
    const int ks   = blockIdx.x >> 6;           // 0..3 key quarter
    const int q0   = qt * QT;
    const int kbase = ks * (NTOK / 4);
    ushort_t* Ps = P + (size_t)ks * NTOK * DIM;

    // ---- Q fragments: wave owns rows [q0+16*wave, +16), full K=512 ----
    bf16x8 qf[16];
    {
        const ushort_t* qrow = Q + (size_t)(q0 + wave * 16 + col) * DIM + quad * 8;
        #pragma unroll
        for (int kk = 0; kk < 16; ++kk)
            qf[kk] = *(const bf16x8*)(qrow + kk * 32);
    }

    // ---- stage K(0) into buf 0: wave stages rows [8w, 8w+8), one row/inst,
    //      source lane-XOR'd so linear LDS holds swizzled content ----
    {
        const size_t base = (size_t)kbase * DIM;
        #pragma unroll
        for (int i = 0; i < 8; ++i) {
            const int r = wave * 8 + i;
            const int sw = (r ^ (r >> 3)) & 7;
            gload_lds16(Q + base + (size_t)r * DIM + ((lane ^ sw) << 3),
                        &Klds[0][r * DIM]);
        }
    }

    f32x4 accO[8][4];
    #pragma unroll
    for (int r = 0; r < 8; ++r)
        #pragma unroll
        for (int c = 0; c < 4; ++c) accO[r][c] = (f32x4){0.f, 0.f, 0.f, 0.f};
    float lsum[4] = {0.f, 0.f, 0.f, 0.f};

    const float sc = 0.04419417382415922f * 1.4426950408889634f;  // 1/sqrt(512)*log2e
    const int wd = wave * 64;

    // swizzle bases: idx = row*stride + ((natural_off8) ^ (swz(row)<<3)),
    // swz(r) = (r ^ (r>>3)) & 7, decomposed into quad/kk parts.
    int rb[4], sx[4];           // K-tile reads (S phase), row = kt*16+col
    #pragma unroll
    for (int kt = 0; kt < 4; ++kt) {
        const int r = kt * 16 + col;
        const int sw = (r ^ (r >> 3)) & 7;
        rb[kt] = r * DIM + ((quad ^ (sw & 3)) << 3);
        sx[kt] = (sw & 4) << 3;
    }
    int pb[8], px[8];           // P reads (PV phase), row = rt*16+col
    #pragma unroll
    for (int rt = 0; rt < 8; ++rt) {
        const int r = rt * 16 + col;
        const int sw = (r ^ (r >> 3)) & 7;
        pb[rt] = r * KTI + ((quad ^ (sw & 3)) << 3);
        px[rt] = (sw & 4) << 3;
    }
    int pw[4], pwx[4];          // P writes, row = wave*16+quad*4+g
    #pragma unroll
    for (int g = 0; g < 4; ++g) {
        const int row = wave * 16 + quad * 4 + g;
        const int sw = (row ^ (row >> 3)) & 7;
        pw[g]  = row * KTI;
        pwx[g] = sw << 3;
    }

    __syncthreads();   // K(0) staged (vmcnt+lgkm drained by syncthreads)

    for (int it = 0; it < NITR; ++it) {
        const int cur = it & 1;
        const ushort_t* Kc = &Klds[cur][0];
        const int j0 = kbase + it * KTI;

        // ---- prefetch K(t+1) into alternate buffer (in flight across the
        //      whole iteration; only drained by end-of-iter __syncthreads) ----
        if (it + 1 < NITR) {
            const size_t base = (size_t)(j0 + KTI) * DIM;
            ushort_t* dst = &Klds[cur ^ 1][0];
            #pragma unroll
            for (int i = 0; i < 8; ++i) {
                const int r = wave * 8 + i;
                const int sw = (r ^ (r >> 3)) & 7;
                gload_lds16(Q + base + (size_t)r * DIM + ((lane ^ sw) << 3),
                            dst + r * DIM);
            }
        }

        // ---- S = Q_tile @ K_tile^T : 4 independent accumulator chains ----
        f32x4 accS[4];
        #pragma unroll
        for (int kt = 0; kt < 4; ++kt) accS[kt] = (f32x4){0.f, 0.f, 0.f, 0.f};
        __builtin_amdgcn_s_setprio(1);
        #pragma unroll
        for (int kk = 0; kk < 16; ++kk)
            #pragma unroll
            for (int kt = 0; kt < 4; ++kt) {
                bf16x8 kb = *(const bf16x8*)&Kc[rb[kt] + ((kk << 5) ^ sx[kt])];
                accS[kt] = mfma16(qf[kk], kb, accS[kt]);
            }
        __builtin_amdgcn_s_setprio(0);

        // ---- V fragments for this iter (global; latency covered by exp+bar) ----
        bf16x8 vA[4], vB[4];
        {
            const ushort_t* eb = embT + (size_t)(wd + col) * NTOK + j0 + quad * 8;
            #pragma unroll
            for (int dt = 0; dt < 4; ++dt) {
                vA[dt] = *(const bf16x8*)(eb + (size_t)(dt * 16) * NTOK);
                vB[dt] = *(const bf16x8*)(eb + (size_t)(dt * 16) * NTOK + 32);
            }
        }

        // ---- P = exp2(S*sc): write swizzled; accumulate row sums ----
        #pragma unroll
        for (int kt = 0; kt < 4; ++kt)
            #pragma unroll
            for (int g = 0; g < 4; ++g) {
                float p = exp2f(fminf(accS[kt][g] * sc, 126.0f));
                lsum[g] += p;
                Plds[pw[g] + ((kt * 16 + col) ^ pwx[g])] = f2bf(p);
            }

        // P visible to all waves; do NOT drain vmcnt (K-prefetch + nothing else)
        asm volatile("s_waitcnt lgkmcnt(0)" ::: "memory");
        __builtin_amdgcn_s_barrier();

        // ---- O += P @ embT^T : P-frags hoisted over the 4 dim-tiles ----
        __builtin_amdgcn_s_setprio(1);
        #pragma unroll
        for (int rt = 0; rt < 8; ++rt) {
            bf16x8 pa0 = *(const bf16x8*)&Plds[pb[rt] + px[rt]];
            bf16x8 pa1 = *(const bf16x8*)&Plds[pb[rt] + (32 ^ px[rt])];
            #pragma unroll
            for (int dt = 0; dt < 4; ++dt) {
                accO[rt][dt] = mfma16(pa0, vA[dt], accO[rt][dt]);
                accO[rt][dt] = mfma16(pa1, vB[dt], accO[rt][dt]);
            }
        }
        __builtin_amdgcn_s_setprio(0);

        // Drain (K(t+1) long since landed) + barrier: next iter may overwrite
        // Klds[cur^1... -> cur] only after everyone is done, and P-writes of
        // t+1 must not race this iter's P-reads.
        __syncthreads();
    }

    // ---- row-sum partials: reduce over col (keys), store per quarter ----
    #pragma unroll
    for (int g = 0; g < 4; ++g) {
        float s = lsum[g];
        s += __shfl_xor(s, 1);
        s += __shfl_xor(s, 2);
        s += __shfl_xor(s, 4);
        s += __shfl_xor(s, 8);
        if (col == 0)
            lsumA[(size_t)ks * NTOK + q0 + wave * 16 + quad * 4 + g] = s;
    }

    // ---- store O partial (pre-normalization) ----
    #pragma unroll
    for (int rt = 0; rt < 8; ++rt)
        #pragma unroll
        for (int dt = 0; dt < 4; ++dt)
            #pragma unroll
            for (int g = 0; g < 4; ++g)
                Ps[(size_t)(q0 + rt * 16 + quad * 4 + g) * DIM + wd + dt * 16 + col]
                    = f2bf(accO[rt][dt][g]);
}

// ---------------------------------------------------------------------------
// Finalize4: T = (P0+P1+P2+P3)/(l0+l1+l2+l3), out = T @ Wv^T + bv.
// ---------------------------------------------------------------------------
__global__ __launch_bounds__(512)
void finalize4_kernel(const int* __restrict__ flag,
                      const ushort_t* __restrict__ P, const float* __restrict__ lsumA,
                      const ushort_t* __restrict__ Wb, const ushort_t* __restrict__ bb,
                      void* __restrict__ Out)
{
    __shared__ ushort_t Alds[64][LDA];
    const bool f32 = (*flag == 0);
    const int tid  = threadIdx.x;
    const int wave = tid >> 6;
    const int lane = tid & 63;
    const int quad = lane >> 4;
    const int col  = lane & 15;
    const int mblk = blockIdx.x * 64;
    const size_t PSZ = (size_t)NTOK * DIM;

    #pragma unroll
    for (int i = 0; i < 8; ++i) {
        int chunk = i * 512 + tid;
        int row = chunk >> 6;
        int k8  = (chunk & 63) * 8;
        int m   = mblk + row;
        float rv = 1.0f / (lsumA[m] + lsumA[NTOK + m]
                         + lsumA[2 * NTOK + m] + lsumA[3 * NTOK + m]);
        size_t off = (size_t)m * 512 + k8;
        bf16x8 v0 = *(const bf16x8*)&P[off];
        bf16x8 v1 = *(const bf16x8*)&P[PSZ + off];
        bf16x8 v2 = *(const bf16x8*)&P[2 * PSZ + off];
        bf16x8 v3 = *(const bf16x8*)&P[3 * PSZ + off];
        bf16x8 t;
        #pragma unroll
        for (int j = 0; j < 8; ++j)
            t[j] = f2bfh(((float)v0[j] + (float)v1[j] + (float)v2[j] + (float)v3[j]) * rv);
        *(bf16x8*)&Alds[row][k8] = t;
    }
    __syncthreads();

    f32x4 acc[4][4];
    #pragma unroll
    for (int r = 0; r < 4; ++r)
        #pragma unroll
        for (int c = 0; c < 4; ++c) acc[r][c] = (f32x4){0.f, 0.f, 0.f, 0.f};

    const int wcol = wave * 64;
    #pragma unroll
    for (int kk = 0; kk < 16; ++kk) {
        bf16x8 a[4];
        #pragma unroll
        for (int r = 0; r < 4; ++r)
            a[r] = *(const bf16x8*)&Alds[r * 16 + col][kk * 32 + quad * 8];
        #pragma unroll
        for (int c = 0; c < 4; ++c) {
            bf16x8 b = *(const bf16x8*)&Wb[(size_t)(wcol + c * 16 + col) * 512
                                           + kk * 32 + quad * 8];
            #pragma unroll
            for (int r = 0; r < 4; ++r)
                acc[r][c] = mfma16(a[r], b, acc[r][c]);
        }
    }

    #pragma unroll
    for (int r = 0; r < 4; ++r)
        #pragma unroll
        for (int c = 0; c < 4; ++c)
            #pragma unroll
            for (int g = 0; g < 4; ++g) {
                int m = mblk + r * 16 + quad * 4 + g;
                int n = wcol + c * 16 + col;
                float v = acc[r][c][g] + bf2f(bb[n]);
                if (f32) ((float*)Out)[(size_t)m * DIM + n] = v;
                else     ((ushort_t*)Out)[(size_t)m * DIM + n] = f2bf(v);
            }
}

// ---------------------------------------------------------------------------
// R13-proven attn64 + finalize (fallback for mid-size workspace).
// ---------------------------------------------------------------------------
__global__ __launch_bounds__(1024)
void attn64_kernel(const ushort_t* __restrict__ Q, const ushort_t* __restrict__ embT,
                   ushort_t* __restrict__ P0, ushort_t* __restrict__ P1,
                   float* __restrict__ lsumA)
{
    __shared__ ushort_t Qlds[64][LDA];
    __shared__ ushort_t Plds[2][64][LDP];
    __shared__ float    Lp[16][64];

    const int tid  = threadIdx.x;
    const int wave = tid >> 6;
    const int lane = tid & 63;
    const int quad = lane >> 4;
    const int col  = lane & 15;
    const int qt   = blockIdx.x & 127;
    const int ks   = blockIdx.x >> 7;
    const int q0   = qt * 64;
    const int kbase = ks * 4096;
    ushort_t* Ps = ks ? P1 : P0;

    #pragma unroll
    for (int i = 0; i < 4; ++i) {
        int chunk = i * 1024 + tid;
        int row = chunk >> 6;
        int k8  = (chunk & 63) * 8;
        *(bf16x8*)&Qlds[row][k8] = *(const bf16x8*)&Q[(size_t)(q0 + row) * 512 + k8];
    }
    __syncthreads();

    f32x4 accO[4][2];
    #pragma unroll
    for (int r = 0; r < 4; ++r)
        #pragma unroll
        for (int c = 0; c < 2; ++c) accO[r][c] = (f32x4){0.f, 0.f, 0.f, 0.f};

    float lsum[4][4];
    #pragma unroll
    for (int r = 0; r < 4; ++r)
        #pragma unroll
        for (int g = 0; g < 4; ++g) lsum[r][g] = 0.f;

    const float sc = 0.04419417382415922f * 1.4426950408889634f;
    const int wd = wave * 32;

    for (int it = 0; it < 16; ++it) {
        const int j0  = kbase + it * 256;
        const int buf = it & 1;

        f32x4 accS[4];
        #pragma unroll
        for (int r = 0; r < 4; ++r) accS[r] = (f32x4){0.f, 0.f, 0.f, 0.f};
        const size_t keyrow = (size_t)(j0 + wave * 16 + col) * 512;
        #pragma unroll
        for (int h = 0; h < 2; ++h) {
            bf16x8 kb[8];
            #pragma unroll
            for (int kk = 0; kk < 8; ++kk)
                kb[kk] = *(const bf16x8*)&Q[keyrow + (h * 8 + kk) * 32 + quad * 8];
            #pragma unroll
            for (int kk = 0; kk < 8; ++kk) {
                const int cofs = (h * 8 + kk) * 32 + quad * 8;
                #pragma unroll
                for (int r = 0; r < 4; ++r) {
                    bf16x8 a = *(const bf16x8*)&Qlds[r * 16 + col][cofs];
                    accS[r] = mfma16(a, kb[kk], accS[r]);
                }
            }
        }

        bf16x8 vbA[8];
        #pragma unroll
        for (int kk = 0; kk < 4; ++kk)
            #pragma unroll
            for (int c = 0; c < 2; ++c)
                vbA[kk * 2 + c] = *(const bf16x8*)&embT[
                    (size_t)(wd + c * 16 + col) * NTOK + j0 + kk * 32 + quad * 8];

        #pragma unroll
        for (int r = 0; r < 4; ++r)
            #pragma unroll
            for (int g = 0; g < 4; ++g) {
                float p = exp2f(fminf(accS[r][g] * sc, 126.0f));
                lsum[r][g] += p;
                Plds[buf][r * 16 + quad * 4 + g][wave * 16 + col] = f2bf(p);
            }

        bf16x8 vbB[8];
        #pragma unroll
        for (int kk = 0; kk < 4; ++kk)
            #pragma unroll
            for (int c = 0; c < 2; ++c)
                vbB[kk * 2 + c] = *(const bf16x8*)&embT[
                    (size_t)(wd + c * 16 + col) * NTOK + j0 + (4 + kk) * 32 + quad * 8];

        __syncthreads();

        #pragma unroll
        for (int kk = 0; kk < 4; ++kk) {
            #pragma unroll
            for (int r = 0; r < 4; ++r) {
                bf16x8 a = *(const bf16x8*)&Plds[buf][r * 16 + col][kk * 32 + quad * 8];
                #pragma unroll
                for (int c = 0; c < 2; ++c)
                    accO[r][c] = mfma16(a, vbA[kk * 2 + c], accO[r][c]);
            }
        }
        #pragma unroll
        for (int kk = 0; kk < 4; ++kk) {
            #pragma unroll
            for (int r = 0; r < 4; ++r) {
                bf16x8 a = *(const bf16x8*)&Plds[buf][r * 16 + col][(4 + kk) * 32 + quad * 8];
                #pragma unroll
                for (int c = 0; c < 2; ++c)
                    accO[r][c] = mfma16(a, vbB[kk * 2 + c], accO[r][c]);
            }
        }
    }

    #pragma unroll
    for (int r = 0; r < 4; ++r)
        #pragma unroll
        for (int g = 0; g < 4; ++g) {
            float s = lsum[r][g];
            s += __shfl_xor(s, 1);
            s += __shfl_xor(s, 2);
            s += __shfl_xor(s, 4);
            s += __shfl_xor(s, 8);
            if (col == 0)
                Lp[wave][r * 16 + quad * 4 + g] = s;
        }
    __syncthreads();
    if (tid < 64) {
        float t = 0.f;
        #pragma unroll
        for (int w = 0; w < 16; ++w) t += Lp[w][tid];
        lsumA[(size_t)ks * NTOK + q0 + tid] = t;
    }

    #pragma unroll
    for (int r = 0; r < 4; ++r)
        #pragma unroll
        for (int c = 0; c < 2; ++c)
            #pragma unroll
            for (int g = 0; g < 4; ++g)
                Ps[(size_t)(q0 + r * 16 + quad * 4 + g) * DIM + wd + c * 16 + col]
                    = f2bf(accO[r][c][g]);
}

__global__ __launch_bounds__(512)
void finalize_kernel(const int* __restrict__ flag,
                     const ushort_t* __restrict__ P0, const ushort_t* __restrict__ P1,
                     const float* __restrict__ lsumA,
                     const ushort_t* __restrict__ Wb, const ushort_t* __restrict__ bb,
                     void* __restrict__ Out)
{
    __shared__ ushort_t Alds[64][LDA];
    const bool f32 = (*flag == 0);
    const int tid  = threadIdx.x;
    const int wave = tid >> 6;
    const int lane = tid & 63;
    const int quad = lane >> 4;
    const int col  = lane & 15;
    const int mblk = blockIdx.x * 64;

    #pragma unroll
    for (int i = 0; i < 8; ++i) {
        int chunk = i * 512 + tid;
        int row = chunk >> 6;
        int k8  = (chunk & 63) * 8;
        int m   = mblk + row;
        float rv = 1.0f / (lsumA[m] + lsumA[NTOK + m]);
        bf16x8 v0 = *(const bf16x8*)&P0[(size_t)m * 512 + k8];
        bf16x8 v1 = *(const bf16x8*)&P1[(size_t)m * 512 + k8];
        bf16x8 t;
        #pragma unroll
        for (int j = 0; j < 8; ++j) t[j] = f2bfh(((float)v0[j] + (float)v1[j]) * rv);
        *(bf16x8*)&Alds[row][k8] = t;
    }
    __syncthreads();

    f32x4 acc[4][4];
    #pragma unroll
    for (int r = 0; r < 4; ++r)
        #pragma unroll
        for (int c = 0; c < 4; ++c) acc[r][c] = (f32x4){0.f, 0.f, 0.f, 0.f};

    const int wcol = wave * 64;
    #pragma unroll
    for (int kk = 0; kk < 16; ++kk) {
        bf16x8 a[4];
        #pragma unroll
        for (int r = 0; r < 4; ++r)
            a[r] = *(const bf16x8*)&Alds[r * 16 + col][kk * 32 + quad * 8];
        #pragma unroll
        for (int c = 0; c < 4; ++c) {
            bf16x8 b = *(const bf16x8*)&Wb[(size_t)(wcol + c * 16 + col) * 512
                                           + kk * 32 + quad * 8];
            #pragma unroll
            for (int r = 0; r < 4; ++r)
                acc[r][c] = mfma16(a[r], b, acc[r][c]);
        }
    }

    #pragma unroll
    for (int r = 0; r < 4; ++r)
        #pragma unroll
        for (int c = 0; c < 4; ++c)
            #pragma unroll
            for (int g = 0; g < 4; ++g) {
                int m = mblk + r * 16 + quad * 4 + g;
                int n = wcol + c * 16 + col;
                float v = acc[r][c][g] + bf2f(bb[n]);
                if (f32) ((float*)Out)[(size_t)m * DIM + n] = v;
                else     ((ushort_t*)Out)[(size_t)m * DIM + n] = f2bf(v);
            }
}

// ---------------------------------------------------------------------------
// Fallback kernels (R13-proven) for smaller workspaces.
// ---------------------------------------------------------------------------
__global__ __launch_bounds__(256)
void transpose_kernel(const int* __restrict__ flag, const void* __restrict__ emb,
                      ushort_t* __restrict__ embT)
{
    __shared__ float tile[64][65];
    const bool f32 = (*flag == 0);
    const int t  = threadIdx.x;
    const int j0 = blockIdx.x * 64;
    const int d0 = blockIdx.y * 64;
    {
        int r = t >> 2, cs = (t & 3) * 16;
        if (f32) {
            const float* src = (const float*)emb + (size_t)(j0 + r) * DIM + d0 + cs;
            #pragma unroll
            for (int i = 0; i < 16; i += 4) {
                float4 v = *(const float4*)(src + i);
                tile[r][cs + i]     = v.x;
                tile[r][cs + i + 1] = v.y;
                tile[r][cs + i + 2] = v.z;
                tile[r][cs + i + 3] = v.w;
            }
        } else {
            const ushort_t* src = (const ushort_t*)emb + (size_t)(j0 + r) * DIM + d0 + cs;
            #pragma unroll
            for (int i = 0; i < 16; ++i) tile[r][cs + i] = bf2f(src[i]);
        }
    }
    __syncthreads();
    {
        int d = t >> 2, js = (t & 3) * 16;
        ushort_t buf[16];
        #pragma unroll
        for (int i = 0; i < 16; ++i) buf[i] = f2bf(tile[js + i][d]);
        ushort_t* dst = embT + (size_t)(d0 + d) * NTOK + j0 + js;
        *(uint4*)dst       = *(uint4*)&buf[0];
        *(uint4*)(dst + 8) = *(uint4*)&buf[8];
    }
}

__global__ __launch_bounds__(512)
void projq_kernel(const int* __restrict__ flag, const void* __restrict__ emb,
                  const void* __restrict__ W, const void* __restrict__ bias,
                  ushort_t* __restrict__ C)
{
    __shared__ ushort_t Alds[32][LDA];
    const bool f32 = (*flag == 0);
    const int tid  = threadIdx.x;
    const int wave = tid >> 6;
    const int lane = tid & 63;
    const int quad = lane >> 4;
    const int col  = lane & 15;
    const int mblk = blockIdx.x * 32;

    #pragma unroll
    for (int i = 0; i < 4; ++i) {
        int chunk = i * 512 + tid;
        int row = chunk >> 6;
        int k8  = (chunk & 63) * 8;
        *(bf16x8*)&Alds[row][k8] = load8(emb, (size_t)(mblk + row) * 512 + k8, f32);
    }
    __syncthreads();

    f32x4 acc[2][4];
    #pragma unroll
    for (int r = 0; r < 2; ++r)
        #pragma unroll
        for (int c = 0; c < 4; ++c) acc[r][c] = (f32x4){0.f, 0.f, 0.f, 0.f};

    const int wcol = wave * 64;
    #pragma unroll
    for (int kk = 0; kk < 16; ++kk) {
        bf16x8 a0 = *(const bf16x8*)&Alds[col][kk * 32 + quad * 8];
        bf16x8 a1 = *(const bf16x8*)&Alds[16 + col][kk * 32 + quad * 8];
        #pragma unroll
        for (int c = 0; c < 4; ++c) {
            bf16x8 b = load8(W, (size_t)(wcol + c * 16 + col) * 512 + kk * 32 + quad * 8, f32);
            acc[0][c] = mfma16(a0, b, acc[0][c]);
            acc[1][c] = mfma16(a1, b, acc[1][c]);
        }
    }

    #pragma unroll
    for (int r = 0; r < 2; ++r)
        #pragma unroll
        for (int c = 0; c < 4; ++c)
            #pragma unroll
            for (int g = 0; g < 4; ++g) {
                int m = mblk + r * 16 + quad * 4 + g;
                int n = wcol + c * 16 + col;
                C[(size_t)m * DIM + n] = f2bf(acc[r][c][g] + loadS(bias, n, f32));
            }
}

template <int VT>
__global__ __launch_bounds__(1024)
void attn_fused_kernel(const int* __restrict__ flag, const ushort_t* __restrict__ Q,
                       const void* __restrict__ embOrT, const void* __restrict__ Wv,
                       const void* __restrict__ bv, void* __restrict__ Out)
{
    __shared__ ushort_t Qlds[32][LDA];
    __shared__ ushort_t Plds[2][32][LDP];
    __shared__ float    Lpart[16][32];

    const bool f32 = (*flag == 0);
    const int tid  = threadIdx.x;
    const int wave = tid >> 6;
    const int lane = tid & 63;
    const int quad = lane >> 4;
    const int col  = lane & 15;
    const int q0   = blockIdx.x * 32;

    #pragma unroll
    for (int i = 0; i < 2; ++i) {
        int chunk = i * 1024 + tid;
        int row = chunk >> 6;
        int k8  = (chunk & 63) * 8;
        *(bf16x8*)&Qlds[row][k8] = *(const bf16x8*)&Q[(size_t)(q0 + row) * 512 + k8];
    }
    __syncthreads();

    f32x4 accO[2][2];
    #pragma unroll
    for (int r = 0; r < 2; ++r)
        #pragma unroll
        for (int c = 0; c < 2; ++c) accO[r][c] = (f32x4){0.f, 0.f, 0.f, 0.f};

    float lsum[2][4];
    #pragma unroll
    for (int r = 0; r < 2; ++r)
        #pragma unroll
        for (int g = 0; g < 4; ++g) lsum[r][g] = 0.f;

    const float sc = 0.04419417382415922f * 1.4426950408889634f;
    const int wOcol = wave * 32;

    for (int it = 0; it < 32; ++it) {
        const int j0  = it * 256;
        const int buf = it & 1;

        bf16x8 kb[16];
        const size_t keyrow = (size_t)(j0 + wave * 16 + col) * 512;
        #pragma unroll
        for (int kk = 0; kk < 16; ++kk)
            kb[kk] = *(const bf16x8*)&Q[keyrow + kk * 32 + quad * 8];

        f32x4 accS[2];
        accS[0] = (f32x4){0.f, 0.f, 0.f, 0.f};
        accS[1] = (f32x4){0.f, 0.f, 0.f, 0.f};
        #pragma unroll
        for (int kk = 0; kk < 16; ++kk) {
            bf16x8 a0 = *(const bf16x8*)&Qlds[col][kk * 32 + quad * 8];
            bf16x8 a1 = *(const bf16x8*)&Qlds[16 + col][kk * 32 + quad * 8];
            accS[0] = mfma16(a0, kb[kk], accS[0]);
            accS[1] = mfma16(a1, kb[kk], accS[1]);
        }

        bf16x8 vb[16];
        #pragma unroll
        for (int kk = 0; kk < 8; ++kk)
            #pragma unroll
            for (int c = 0; c < 2; ++c) {
                if (VT) {
                    vb[kk * 2 + c] = *(const bf16x8*)((const ushort_t*)embOrT
                        + (size_t)(wOcol + c * 16 + col) * NTOK + j0 + kk * 32 + quad * 8);
                } else {
                    size_t base = (size_t)(j0 + kk * 32 + quad * 8) * 512 + (wOcol + c * 16 + col);
                    bf16x8 b;
                    if (f32) {
                        const float* bp = (const float*)embOrT + base;
                        #pragma unroll
                        for (int j = 0; j < 8; ++j) b[j] = f2bfh(bp[(size_t)j * 512]);
                    } else {
                        const __bf16* bp = (const __bf16*)embOrT + base;
                        #pragma unroll
                        for (int j = 0; j < 8; ++j) b[j] = bp[(size_t)j * 512];
                    }
                    vb[kk * 2 + c] = b;
                }
            }

        #pragma unroll
        for (int r = 0; r < 2; ++r)
            #pragma unroll
            for (int g = 0; g < 4; ++g) {
                float p = exp2f(fminf(accS[r][g] * sc, 126.0f));
                lsum[r][g] += p;
                Plds[buf][r * 16 + quad * 4 + g][wave * 16 + col] = f2bf(p);
            }

        __syncthreads();

        #pragma unroll
        for (int kk = 0; kk < 8; ++kk) {
            bf16x8 a0 = *(const bf16x8*)&Plds[buf][col][kk * 32 + quad * 8];
            bf16x8 a1 = *(const bf16x8*)&Plds[buf][16 + col][kk * 32 + quad * 8];
            #pragma unroll
            for (int c = 0; c < 2; ++c) {
                accO[0][c] = mfma16(a0, vb[kk * 2 + c], accO[0][c]);
                accO[1][c] = mfma16(a1, vb[kk * 2 + c], accO[1][c]);
            }
        }
    }

    #pragma unroll
    for (int r = 0; r < 2; ++r)
        #pragma unroll
        for (int g = 0; g < 4; ++g) {
            float s = lsum[r][g];
            s += __shfl_xor(s, 1);
            s += __shfl_xor(s, 2);
            s += __shfl_xor(s, 4);
            s += __shfl_xor(s, 8);
            lsum[r][g] = s;
        }
    if (col == 0) {
        #pragma unroll
        for (int r = 0; r < 2; ++r)
            #pragma unroll
            for (int g = 0; g < 4; ++g)
                Lpart[wave][r * 16 + quad * 4 + g] = lsum[r][g];
    }
    __syncthreads();

    #pragma unroll
    for (int r = 0; r < 2; ++r) {
        float rinv[4];
        #pragma unroll
        for (int g = 0; g < 4; ++g) {
            float t = 0.f;
            #pragma unroll
            for (int w = 0; w < 16; ++w) t += Lpart[w][r * 16 + quad * 4 + g];
            rinv[g] = 1.0f / t;
        }
        #pragma unroll
        for (int c = 0; c < 2; ++c)
            #pragma unroll
            for (int g = 0; g < 4; ++g)
                Qlds[r * 16 + quad * 4 + g][wOcol + c * 16 + col] = f2bf(accO[r][c][g] * rinv[g]);
    }
    __syncthreads();

    f32x4 acc2[2][2];
    #pragma unroll
    for (int r = 0; r < 2; ++r)
        #pragma unroll
        for (int c = 0; c < 2; ++c) acc2[r][c] = (f32x4){0.f, 0.f, 0.f, 0.f};

    #pragma unroll
    for (int kk = 0; kk < 16; ++kk) {
        bf16x8 a0 = *(const bf16x8*)&Qlds[col][kk * 32 + quad * 8];
        bf16x8 a1 = *(const bf16x8*)&Qlds[16 + col][kk * 32 + quad * 8];
        #pragma unroll
        for (int c = 0; c < 2; ++c) {
            bf16x8 b = load8(Wv, (size_t)(wOcol + c * 16 + col) * 512 + kk * 32 + quad * 8, f32);
            acc2[0][c] = mfma16(a0, b, acc2[0][c]);
            acc2[1][c] = mfma16(a1, b, acc2[1][c]);
        }
    }

    #pragma unroll
    for (int r = 0; r < 2; ++r)
        #pragma unroll
        for (int c = 0; c < 2; ++c)
            #pragma unroll
            for (int g = 0; g < 4; ++g) {
                int m = q0 + r * 16 + quad * 4 + g;
                int n = wOcol + c * 16 + col;
                float v = acc2[r][c][g] + loadS(bv, n, f32);
                if (f32) ((float*)Out)[(size_t)m * DIM + n] = v;
                else     ((ushort_t*)Out)[(size_t)m * DIM + n] = f2bf(v);
            }
}

extern "C" void kernel_launch(void* const* d_in, const int* in_sizes, int n_in,
                              void* d_out, int out_size, void* d_ws, size_t ws_size,
                              hipStream_t stream)
{
    const void* emb = d_in[0];
    const void* Wqk = d_in[1];
    const void* bqk = d_in[2];
    const void* Wv  = d_in[3];
    const void* bv  = d_in[4];

    char* W = (char*)d_ws;
    int* flag = (int*)W;

    // New (R15) layout: flag | lsum4 (128KB) | Wqkb | Wvb | bqkb | bvb | embT | Qws | P[4]
    const size_t needC = 64 + 4 * (size_t)NTOK * 4 + 2 * (size_t)DIM * DIM * 2
                       + 2 * DIM * 2 + 6 * (size_t)NTOK * DIM * 2;   // ~49.1 MB
    // Old (R14) layout
    const size_t needA = 64 + 65536 + 2 * (size_t)DIM * DIM * 2 + 2 * DIM * 2
                       + 4 * (size_t)NTOK * DIM * 2;                  // ~33.1 MB
    const size_t needB = 64 + 2 * (size_t)NTOK * DIM * 2;             // 16.03 MB

    detect_kernel<<<dim3(1), dim3(64), 0, stream>>>((const ushort_t*)emb, flag);

    if (ws_size >= needC) {
        float*    lsum4 = (float*)(W + 64);                          // 128 KB
        ushort_t* Wqkb  = (ushort_t*)(W + 64 + 4 * (size_t)NTOK * 4);
        ushort_t* Wvb   = Wqkb + (size_t)DIM * DIM;
        ushort_t* bqkb  = Wvb + (size_t)DIM * DIM;
        ushort_t* bvb   = bqkb + DIM;
        ushort_t* embT  = bvb + DIM;                                 // 8 MB
        ushort_t* Qws   = embT + (size_t)DIM * NTOK;                 // 8 MB
        ushort_t* P4    = Qws + (size_t)DIM * NTOK;                  // 4 x 8 MB

        prep_kernel<<<dim3(128), dim3(256), 0, stream>>>(flag, Wqk, bqk, Wv, bv,
                                                         Wqkb, bqkb, Wvb, bvb);
        projqT_kernel<<<dim3(NTOK / 64), dim3(512), 0, stream>>>(flag, emb, Wqkb, bqkb,
                                                                 Qws, embT);
        attn128_kernel<<<dim3(256), dim3(512), 0, stream>>>(Qws, embT, P4, lsum4);
        finalize4_kernel<<<dim3(NTOK / 64), dim3(512), 0, stream>>>(flag, P4, lsum4,
                                                                    Wvb, bvb, d_out);
    } else if (ws_size >= needA) {
        float*    lsumA = (float*)(W + 64);                          // 64 KB
        ushort_t* Wqkb  = (ushort_t*)(W + 64 + 65536);
        ushort_t* Wvb   = Wqkb + (size_t)DIM * DIM;
        ushort_t* bqkb  = Wvb + (size_t)DIM * DIM;
        ushort_t* bvb   = bqkb + DIM;
        ushort_t* embT  = bvb + DIM;
        ushort_t* Qws   = embT + (size_t)DIM * NTOK;
        ushort_t* P0    = Qws + (size_t)DIM * NTOK;
        ushort_t* P1    = P0 + (size_t)NTOK * DIM;

        prep_kernel<<<dim3(128), dim3(256), 0, stream>>>(flag, Wqk, bqk, Wv, bv,
                                                         Wqkb, bqkb, Wvb, bvb);
        projqT_kernel<<<dim3(NTOK / 64), dim3(512), 0, stream>>>(flag, emb, Wqkb, bqkb,
                                                                 Qws, embT);
        attn64_kernel<<<dim3(256), dim3(1024), 0, stream>>>(Qws, embT, P0, P1, lsumA);
        finalize_kernel<<<dim3(NTOK / 64), dim3(512), 0, stream>>>(flag, P0, P1, lsumA,
                                                                   Wvb, bvb, d_out);
    } else if (ws_size >= needB) {
        ushort_t* embT2 = (ushort_t*)(W + 64);
        ushort_t* Qws2  = embT2 + (size_t)DIM * NTOK;
        transpose_kernel<<<dim3(128, 8), dim3(256), 0, stream>>>(flag, emb, embT2);
        projq_kernel<<<dim3(NTOK / 32), dim3(512), 0, stream>>>(flag, emb, Wqk, bqk, Qws2);
        attn_fused_kernel<1><<<dim3(NTOK / 32), dim3(1024), 0, stream>>>(
            flag, Qws2, embT2, Wv, bv, d_out);
    } else {
        ushort_t* Qsm = (ushort_t*)(W + 64);
        projq_kernel<<<dim3(NTOK / 32), dim3(512), 0, stream>>>(flag, emb, Wqk, bqk, Qsm);
        attn_fused_kernel<0><<<dim3(NTOK / 32), dim3(1024), 0, stream>>>(
            flag, Qsm, emb, Wv, bv, d_out);
    }
}

// Round 2
// 441.013 us; speedup vs baseline: 1.4551x; 1.4551x over previous
//
#include <hip/hip_runtime.h>
#include <hip/hip_bf16.h>

// N=8192, D=512.  Q = emb@Wqk^T+bqk (K==Q); out = softmax(QK^T/sqrt(512)) @ V.
// Softmax rows sum to 1 => out = (softmax(S)@emb) @ Wv^T + bv (V never built).
// R16: R15's attn128 spilled (~270 reg demand vs 128 cap -> 470MB scratch
// FETCH, 531us). v2 keeps Tq=128 (halves cache-fabric traffic vs attn64's
// 2.05GB) but reverts to the attn64-proven placement: Q staged once in padded
// LDS [128][520], K per-wave direct-global (4-wave L1 share), P single-buffer
// [128][72], 1024 thr / 16 waves (4/SIMD TLP). Register plan: accO 64 (AGPR)
// + ~50 VGPR transients, peak ~114 < 128. LDS 153.6KB. 2 barriers/iter.
// Fallbacks (attn64 etc.) unchanged.

#define NTOK 8192
#define DIM  512

typedef unsigned short ushort_t;
typedef unsigned int u32;
typedef __attribute__((ext_vector_type(8))) __bf16 bf16x8;
typedef __attribute__((ext_vector_type(4))) float f32x4;

__device__ __forceinline__ float bf2f(ushort_t u) {
    union { unsigned int i; float f; } v; v.i = ((unsigned int)u) << 16; return v.f;
}
__device__ __forceinline__ ushort_t f2bf(float f) {
    union { float f; unsigned int i; } v; v.f = f;
    unsigned int b = v.i;
    return (ushort_t)((b + 0x7FFFu + ((b >> 16) & 1u)) >> 16);   // RNE
}
__device__ __forceinline__ __bf16 f2bfh(float f) {
    union { ushort_t u; __bf16 h; } c; c.u = f2bf(f); return c.h;
}
__device__ __forceinline__ f32x4 mfma16(bf16x8 a, bf16x8 b, f32x4 c) {
    return __builtin_amdgcn_mfma_f32_16x16x32_bf16(a, b, c, 0, 0, 0);
}
__device__ __forceinline__ bf16x8 load8(const void* p, size_t idx, bool f32) {
    if (f32) {
        const float* f = (const float*)p + idx;
        bf16x8 r;
        #pragma unroll
        for (int j = 0; j < 8; ++j) r[j] = f2bfh(f[j]);
        return r;
    }
    return *(const bf16x8*)((const ushort_t*)p + idx);
}
__device__ __forceinline__ float loadS(const void* p, size_t idx, bool f32) {
    return f32 ? ((const float*)p)[idx] : bf2f(((const ushort_t*)p)[idx]);
}

#define LDA 520   // 260 dw, %32=4: uniform bank spread for b128 row reads
#define LDP 264
#define LDP2 72   // P tile row stride (64 keys + 8 pad): 36 dw %32=4

// ---------------------------------------------------------------------------
// Dtype probe: flag=1 => bf16 data, flag=0 => fp32.
// ---------------------------------------------------------------------------
__global__ void detect_kernel(const ushort_t* __restrict__ emb, int* __restrict__ flag)
{
    int lane = threadIdx.x;
    int cnt = 0;
    #pragma unroll
    for (int i = 0; i < 8; ++i) {
        ushort_t u = emb[(size_t)(lane * 8 + i) * 2];
        int a = u & 0x7FFF;
        int e = (u >> 7) & 0xFF;
        if (a == 0 || (e >= 111 && e <= 143)) cnt++;
    }
    cnt += __shfl_xor(cnt, 1);  cnt += __shfl_xor(cnt, 2);  cnt += __shfl_xor(cnt, 4);
    cnt += __shfl_xor(cnt, 8);  cnt += __shfl_xor(cnt, 16); cnt += __shfl_xor(cnt, 32);
    if (lane == 0) *flag = (cnt >= 460) ? 1 : 0;
}

// ---------------------------------------------------------------------------
// Prep: convert Wqk, Wv (512x512) + bqk, bv (512) to bf16 in ws.
// ---------------------------------------------------------------------------
__global__ __launch_bounds__(256)
void prep_kernel(const int* __restrict__ flag,
                 const void* __restrict__ Wqk, const void* __restrict__ bqk,
                 const void* __restrict__ Wv,  const void* __restrict__ bv,
                 ushort_t* __restrict__ Wqkb, ushort_t* __restrict__ bqkb,
                 ushort_t* __restrict__ Wvb,  ushort_t* __restrict__ bvb)
{
    const bool f32 = (*flag == 0);
    size_t gid = (size_t)blockIdx.x * 256 + threadIdx.x;   // 32768 threads
    size_t base = gid * 8;                                  // 262144 = 512*512
    *(bf16x8*)&Wqkb[base] = load8(Wqk, base, f32);
    *(bf16x8*)&Wvb[base]  = load8(Wv,  base, f32);
    if (gid < 64) {
        *(bf16x8*)&bqkb[base] = load8(bqk, base, f32);
        *(bf16x8*)&bvb[base]  = load8(bv,  base, f32);
    }
}

// ---------------------------------------------------------------------------
// Fused: Q[64 rows] = emb@Wqk^T+bqk AND embT columns, from one staged tile.
// ---------------------------------------------------------------------------
__global__ __launch_bounds__(512)
void projqT_kernel(const int* __restrict__ flag, const void* __restrict__ emb,
                   const ushort_t* __restrict__ Wb, const ushort_t* __restrict__ bb,
                   ushort_t* __restrict__ C, ushort_t* __restrict__ embT)
{
    __shared__ ushort_t Alds[64][LDA];   // 66,560 B
    const bool f32 = (*flag == 0);
    const int tid  = threadIdx.x;
    const int wave = tid >> 6;
    const int lane = tid & 63;
    const int quad = lane >> 4;
    const int col  = lane & 15;
    const int mblk = blockIdx.x * 64;

    #pragma unroll
    for (int i = 0; i < 8; ++i) {
        int chunk = i * 512 + tid;
        int row = chunk >> 6;
        int k8  = (chunk & 63) * 8;
        *(bf16x8*)&Alds[row][k8] = load8(emb, (size_t)(mblk + row) * 512 + k8, f32);
    }
    __syncthreads();

    // ---- transpose store: thread t owns dim t, 64 tokens (128 B) ----
    {
        ushort_t buf[64];
        #pragma unroll
        for (int r = 0; r < 64; ++r) buf[r] = Alds[r][tid];
        ushort_t* dst = embT + (size_t)tid * NTOK + mblk;
        #pragma unroll
        for (int i = 0; i < 8; ++i)
            *(uint4*)(dst + i * 8) = *(uint4*)&buf[i * 8];
    }

    // ---- Q projection (64 rows x this wave's 64 cols) ----
    f32x4 acc[4][4];
    #pragma unroll
    for (int r = 0; r < 4; ++r)
        #pragma unroll
        for (int c = 0; c < 4; ++c) acc[r][c] = (f32x4){0.f, 0.f, 0.f, 0.f};

    const int wcol = wave * 64;
    #pragma unroll
    for (int kk = 0; kk < 16; ++kk) {
        bf16x8 a[4];
        #pragma unroll
        for (int r = 0; r < 4; ++r)
            a[r] = *(const bf16x8*)&Alds[r * 16 + col][kk * 32 + quad * 8];
        #pragma unroll
        for (int c = 0; c < 4; ++c) {
            bf16x8 b = *(const bf16x8*)&Wb[(size_t)(wcol + c * 16 + col) * 512
                                           + kk * 32 + quad * 8];
            #pragma unroll
            for (int r = 0; r < 4; ++r)
                acc[r][c] = mfma16(a[r], b, acc[r][c]);
        }
    }

    #pragma unroll
    for (int r = 0; r < 4; ++r)
        #pragma unroll
        for (int c = 0; c < 4; ++c)
            #pragma unroll
            for (int g = 0; g < 4; ++g) {
                int m = mblk + r * 16 + quad * 4 + g;
                int n = wcol + c * 16 + col;
                C[(size_t)m * DIM + n] = f2bf(acc[r][c][g] + bf2f(bb[n]));
            }
}

// ---------------------------------------------------------------------------
// attn128 v2 (R16): 256 blocks = 64 q-tiles (Tq=128) x 4 key-quarters,
// 1024 thr = 16 waves. Q tile staged once in padded LDS (attn64-proven LDA).
// Per iter (KT=64 keys): wave w: kt = w&3 (its 16 keys, direct global, 4-wave
// L1 share), rp = w>>2 (its 32 q-rows): S = 2 fragments. P via single padded
// LDS buffer; PV: wave owns 32 dims, accO[8][2] (AGPR).
// ---------------------------------------------------------------------------
#define QT2  128
#define KT2  64
#define NIT2 32

__global__ __launch_bounds__(1024)
void attn128_kernel(const ushort_t* __restrict__ Q, const ushort_t* __restrict__ embT,
                    ushort_t* __restrict__ P, float* __restrict__ lsumA)
{
    __shared__ ushort_t Qlds[QT2][LDA];    // 133,120 B
    __shared__ ushort_t Plds[QT2][LDP2];   //  18,432 B
    __shared__ float    Lp[4][QT2];        //   2,048 B  (total 153,600)

    const int tid  = threadIdx.x;
    const int wave = tid >> 6;
    const int lane = tid & 63;
    const int quad = lane >> 4;
    const int col  = lane & 15;
    const int qt   = blockIdx.x & 63;
    const int ks   = blockIdx.x >> 6;           // 0..3 key quarter
    const int q0   = qt * QT2;
    const int kbase = ks * (NTOK / 4);
    ushort_t* Ps = P + (size_t)ks * NTOK * DIM;

    const int kt = wave & 3;                    // S key-tile owner
    const int rp = wave >> 2;                   // S row-pair owner (32 rows)
    const int wd = wave * 32;                   // PV dim range

    // ---- stage Q tile (128 rows x 512) into LDS, once ----
    #pragma unroll
    for (int i = 0; i < 8; ++i) {
        int chunk = i * 1024 + tid;
        int row = chunk >> 6;
        int k8  = (chunk & 63) * 8;
        *(bf16x8*)&Qlds[row][k8] = *(const bf16x8*)&Q[(size_t)(q0 + row) * 512 + k8];
    }
    __syncthreads();

    f32x4 accO[8][2];
    #pragma unroll
    for (int r = 0; r < 8; ++r) {
        accO[r][0] = (f32x4){0.f, 0.f, 0.f, 0.f};
        accO[r][1] = (f32x4){0.f, 0.f, 0.f, 0.f};
    }
    float lsum[2][4];
    #pragma unroll
    for (int i = 0; i < 2; ++i)
        #pragma unroll
        for (int g = 0; g < 4; ++g) lsum[i][g] = 0.f;

    const float sc = 0.04419417382415922f * 1.4426950408889634f;  // 1/sqrt(512)*log2e

    for (int it = 0; it < NIT2; ++it) {
        const int j0 = kbase + it * KT2;

        // ---- S = Q[rp rows] @ K[kt keys]^T, K direct from global ----
        f32x4 accS[2];
        accS[0] = (f32x4){0.f, 0.f, 0.f, 0.f};
        accS[1] = (f32x4){0.f, 0.f, 0.f, 0.f};
        const ushort_t* kptr = Q + (size_t)(j0 + kt * 16 + col) * DIM + quad * 8;
        #pragma unroll
        for (int R = 0; R < 4; ++R) {
            bf16x8 kb[4];
            #pragma unroll
            for (int j = 0; j < 4; ++j)
                kb[j] = *(const bf16x8*)(kptr + (R * 4 + j) * 32);
            #pragma unroll
            for (int j = 0; j < 4; ++j) {
                const int kk = R * 4 + j;
                #pragma unroll
                for (int i = 0; i < 2; ++i) {
                    bf16x8 a = *(const bf16x8*)&Qlds[rp * 32 + i * 16 + col]
                                                    [kk * 32 + quad * 8];
                    accS[i] = mfma16(a, kb[j], accS[i]);
                }
            }
        }

        // ---- P = exp2(S*sc) -> Plds; row-sum partials ----
        #pragma unroll
        for (int i = 0; i < 2; ++i)
            #pragma unroll
            for (int g = 0; g < 4; ++g) {
                float p = exp2f(fminf(accS[i][g] * sc, 126.0f));
                lsum[i][g] += p;
                Plds[rp * 32 + i * 16 + quad * 4 + g][kt * 16 + col] = f2bf(p);
            }

        // ---- V fragments (issued pre-barrier; in flight across it) ----
        __builtin_amdgcn_sched_barrier(0);   // keep vb loads here (not hoisted)
        bf16x8 vb[2][2];
        {
            const ushort_t* eb = embT + (size_t)(wd + col) * NTOK + j0 + quad * 8;
            #pragma unroll
            for (int c = 0; c < 2; ++c) {
                vb[c][0] = *(const bf16x8*)(eb + (size_t)(c * 16) * NTOK);
                vb[c][1] = *(const bf16x8*)(eb + (size_t)(c * 16) * NTOK + 32);
            }
        }

        // ---- B1: P visible to all waves (LDS only; vmem stays in flight) ----
        asm volatile("s_waitcnt lgkmcnt(0)" ::: "memory");
        __builtin_amdgcn_s_barrier();
        __builtin_amdgcn_sched_barrier(0);

        // ---- O += P @ embT^T (wave's 32 dims, all 128 rows) ----
        #pragma unroll
        for (int rt = 0; rt < 8; ++rt) {
            bf16x8 p0 = *(const bf16x8*)&Plds[rt * 16 + col][quad * 8];
            bf16x8 p1 = *(const bf16x8*)&Plds[rt * 16 + col][32 + quad * 8];
            #pragma unroll
            for (int c = 0; c < 2; ++c) {
                accO[rt][c] = mfma16(p0, vb[c][0], accO[rt][c]);
                accO[rt][c] = mfma16(p1, vb[c][1], accO[rt][c]);
            }
        }

        // ---- B2: all P-reads done before next iter's P-writes ----
        __syncthreads();
    }

    // ---- row-sum partials: reduce over col (16 keys), combine 4 kt waves ----
    #pragma unroll
    for (int i = 0; i < 2; ++i)
        #pragma unroll
        for (int g = 0; g < 4; ++g) {
            float s = lsum[i][g];
            s += __shfl_xor(s, 1);
            s += __shfl_xor(s, 2);
            s += __shfl_xor(s, 4);
            s += __shfl_xor(s, 8);
            if (col == 0)
                Lp[kt][rp * 32 + i * 16 + quad * 4 + g] = s;
        }
    __syncthreads();
    if (tid < QT2) {
        float t = Lp[0][tid] + Lp[1][tid] + Lp[2][tid] + Lp[3][tid];
        lsumA[(size_t)ks * NTOK + q0 + tid] = t;
    }

    // ---- store O partial (pre-normalization) ----
    #pragma unroll
    for (int rt = 0; rt < 8; ++rt)
        #pragma unroll
        for (int c = 0; c < 2; ++c)
            #pragma unroll
            for (int g = 0; g < 4; ++g)
                Ps[(size_t)(q0 + rt * 16 + quad * 4 + g) * DIM + wd + c * 16 + col]
                    = f2bf(accO[rt][c][g]);
}

// ---------------------------------------------------------------------------
// Finalize4: T = (P0+P1+P2+P3)/(l0+l1+l2+l3), out = T @ Wv^T + bv.
// ---------------------------------------------------------------------------
__global__ __launch_bounds__(512)
void finalize4_kernel(const int* __restrict__ flag,
                      const ushort_t* __restrict__ P, const float* __restrict__ lsumA,
                      const ushort_t* __restrict__ Wb, const ushort_t* __restrict__ bb,
                      void* __restrict__ Out)
{
    __shared__ ushort_t Alds[64][LDA];
    const bool f32 = (*flag == 0);
    const int tid  = threadIdx.x;
    const int wave = tid >> 6;
    const int lane = tid & 63;
    const int quad = lane >> 4;
    const int col  = lane & 15;
    const int mblk = blockIdx.x * 64;
    const size_t PSZ = (size_t)NTOK * DIM;

    #pragma unroll
    for (int i = 0; i < 8; ++i) {
        int chunk = i * 512 + tid;
        int row = chunk >> 6;
        int k8  = (chunk & 63) * 8;
        int m   = mblk + row;
        float rv = 1.0f / (lsumA[m] + lsumA[NTOK + m]
                         + lsumA[2 * NTOK + m] + lsumA[3 * NTOK + m]);
        size_t off = (size_t)m * 512 + k8;
        bf16x8 v0 = *(const bf16x8*)&P[off];
        bf16x8 v1 = *(const bf16x8*)&P[PSZ + off];
        bf16x8 v2 = *(const bf16x8*)&P[2 * PSZ + off];
        bf16x8 v3 = *(const bf16x8*)&P[3 * PSZ + off];
        bf16x8 t;
        #pragma unroll
        for (int j = 0; j < 8; ++j)
            t[j] = f2bfh(((float)v0[j] + (float)v1[j] + (float)v2[j] + (float)v3[j]) * rv);
        *(bf16x8*)&Alds[row][k8] = t;
    }
    __syncthreads();

    f32x4 acc[4][4];
    #pragma unroll
    for (int r = 0; r < 4; ++r)
        #pragma unroll
        for (int c = 0; c < 4; ++c) acc[r][c] = (f32x4){0.f, 0.f, 0.f, 0.f};

    const int wcol = wave * 64;
    #pragma unroll
    for (int kk = 0; kk < 16; ++kk) {
        bf16x8 a[4];
        #pragma unroll
        for (int r = 0; r < 4; ++r)
            a[r] = *(const bf16x8*)&Alds[r * 16 + col][kk * 32 + quad * 8];
        #pragma unroll
        for (int c = 0; c < 4; ++c) {
            bf16x8 b = *(const bf16x8*)&Wb[(size_t)(wcol + c * 16 + col) * 512
                                           + kk * 32 + quad * 8];
            #pragma unroll
            for (int r = 0; r < 4; ++r)
                acc[r][c] = mfma16(a[r], b, acc[r][c]);
        }
    }

    #pragma unroll
    for (int r = 0; r < 4; ++r)
        #pragma unroll
        for (int c = 0; c < 4; ++c)
            #pragma unroll
            for (int g = 0; g < 4; ++g) {
                int m = mblk + r * 16 + quad * 4 + g;
                int n = wcol + c * 16 + col;
                float v = acc[r][c][g] + bf2f(bb[n]);
                if (f32) ((float*)Out)[(size_t)m * DIM + n] = v;
                else     ((ushort_t*)Out)[(size_t)m * DIM + n] = f2bf(v);
            }
}

// ---------------------------------------------------------------------------
// R13-proven attn64 + finalize (fallback for mid-size workspace).
// ---------------------------------------------------------------------------
__global__ __launch_bounds__(1024)
void attn64_kernel(const ushort_t* __restrict__ Q, const ushort_t* __restrict__ embT,
                   ushort_t* __restrict__ P0, ushort_t* __restrict__ P1,
                   float* __restrict__ lsumA)
{
    __shared__ ushort_t Qlds[64][LDA];
    __shared__ ushort_t Plds[2][64][LDP];
    __shared__ float    Lp[16][64];

    const int tid  = threadIdx.x;
    const int wave = tid >> 6;
    const int lane = tid & 63;
    const int quad = lane >> 4;
    const int col  = lane & 15;
    const int qt   = blockIdx.x & 127;
    const int ks   = blockIdx.x >> 7;
    const int q0   = qt * 64;
    const int kbase = ks * 4096;
    ushort_t* Ps = ks ? P1 : P0;

    #pragma unroll
    for (int i = 0; i < 4; ++i) {
        int chunk = i * 1024 + tid;
        int row = chunk >> 6;
        int k8  = (chunk & 63) * 8;
        *(bf16x8*)&Qlds[row][k8] = *(const bf16x8*)&Q[(size_t)(q0 + row) * 512 + k8];
    }
    __syncthreads();

    f32x4 accO[4][2];
    #pragma unroll
    for (int r = 0; r < 4; ++r)
        #pragma unroll
        for (int c = 0; c < 2; ++c) accO[r][c] = (f32x4){0.f, 0.f, 0.f, 0.f};

    float lsum[4][4];
    #pragma unroll
    for (int r = 0; r < 4; ++r)
        #pragma unroll
        for (int g = 0; g < 4; ++g) lsum[r][g] = 0.f;

    const float sc = 0.04419417382415922f * 1.4426950408889634f;
    const int wd = wave * 32;

    for (int it = 0; it < 16; ++it) {
        const int j0  = kbase + it * 256;
        const int buf = it & 1;

        f32x4 accS[4];
        #pragma unroll
        for (int r = 0; r < 4; ++r) accS[r] = (f32x4){0.f, 0.f, 0.f, 0.f};
        const size_t keyrow = (size_t)(j0 + wave * 16 + col) * 512;
        #pragma unroll
        for (int h = 0; h < 2; ++h) {
            bf16x8 kb[8];
            #pragma unroll
            for (int kk = 0; kk < 8; ++kk)
                kb[kk] = *(const bf16x8*)&Q[keyrow + (h * 8 + kk) * 32 + quad * 8];
            #pragma unroll
            for (int kk = 0; kk < 8; ++kk) {
                const int cofs = (h * 8 + kk) * 32 + quad * 8;
                #pragma unroll
                for (int r = 0; r < 4; ++r) {
                    bf16x8 a = *(const bf16x8*)&Qlds[r * 16 + col][cofs];
                    accS[r] = mfma16(a, kb[kk], accS[r]);
                }
            }
        }

        bf16x8 vbA[8];
        #pragma unroll
        for (int kk = 0; kk < 4; ++kk)
            #pragma unroll
            for (int c = 0; c < 2; ++c)
                vbA[kk * 2 + c] = *(const bf16x8*)&embT[
                    (size_t)(wd + c * 16 + col) * NTOK + j0 + kk * 32 + quad * 8];

        #pragma unroll
        for (int r = 0; r < 4; ++r)
            #pragma unroll
            for (int g = 0; g < 4; ++g) {
                float p = exp2f(fminf(accS[r][g] * sc, 126.0f));
                lsum[r][g] += p;
                Plds[buf][r * 16 + quad * 4 + g][wave * 16 + col] = f2bf(p);
            }

        bf16x8 vbB[8];
        #pragma unroll
        for (int kk = 0; kk < 4; ++kk)
            #pragma unroll
            for (int c = 0; c < 2; ++c)
                vbB[kk * 2 + c] = *(const bf16x8*)&embT[
                    (size_t)(wd + c * 16 + col) * NTOK + j0 + (4 + kk) * 32 + quad * 8];

        __syncthreads();

        #pragma unroll
        for (int kk = 0; kk < 4; ++kk) {
            #pragma unroll
            for (int r = 0; r < 4; ++r) {
                bf16x8 a = *(const bf16x8*)&Plds[buf][r * 16 + col][kk * 32 + quad * 8];
                #pragma unroll
                for (int c = 0; c < 2; ++c)
                    accO[r][c] = mfma16(a, vbA[kk * 2 + c], accO[r][c]);
            }
        }
        #pragma unroll
        for (int kk = 0; kk < 4; ++kk) {
            #pragma unroll
            for (int r = 0; r < 4; ++r) {
                bf16x8 a = *(const bf16x8*)&Plds[buf][r * 16 + col][(4 + kk) * 32 + quad * 8];
                #pragma unroll
                for (int c = 0; c < 2; ++c)
                    accO[r][c] = mfma16(a, vbB[kk * 2 + c], accO[r][c]);
            }
        }
    }

    #pragma unroll
    for (int r = 0; r < 4; ++r)
        #pragma unroll
        for (int g = 0; g < 4; ++g) {
            float s = lsum[r][g];
            s += __shfl_xor(s, 1);
            s += __shfl_xor(s, 2);
            s += __shfl_xor(s, 4);
            s += __shfl_xor(s, 8);
            if (col == 0)
                Lp[wave][r * 16 + quad * 4 + g] = s;
        }
    __syncthreads();
    if (tid < 64) {
        float t = 0.f;
        #pragma unroll
        for (int w = 0; w < 16; ++w) t += Lp[w][tid];
        lsumA[(size_t)ks * NTOK + q0 + tid] = t;
    }

    #pragma unroll
    for (int r = 0; r < 4; ++r)
        #pragma unroll
        for (int c = 0; c < 2; ++c)
            #pragma unroll
            for (int g = 0; g < 4; ++g)
                Ps[(size_t)(q0 + r * 16 + quad * 4 + g) * DIM + wd + c * 16 + col]
                    = f2bf(accO[r][c][g]);
}

__global__ __launch_bounds__(512)
void finalize_kernel(const int* __restrict__ flag,
                     const ushort_t* __restrict__ P0, const ushort_t* __restrict__ P1,
                     const float* __restrict__ lsumA,
                     const ushort_t* __restrict__ Wb, const ushort_t* __restrict__ bb,
                     void* __restrict__ Out)
{
    __shared__ ushort_t Alds[64][LDA];
    const bool f32 = (*flag == 0);
    const int tid  = threadIdx.x;
    const int wave = tid >> 6;
    const int lane = tid & 63;
    const int quad = lane >> 4;
    const int col  = lane & 15;
    const int mblk = blockIdx.x * 64;

    #pragma unroll
    for (int i = 0; i < 8; ++i) {
        int chunk = i * 512 + tid;
        int row = chunk >> 6;
        int k8  = (chunk & 63) * 8;
        int m   = mblk + row;
        float rv = 1.0f / (lsumA[m] + lsumA[NTOK + m]);
        bf16x8 v0 = *(const bf16x8*)&P0[(size_t)m * 512 + k8];
        bf16x8 v1 = *(const bf16x8*)&P1[(size_t)m * 512 + k8];
        bf16x8 t;
        #pragma unroll
        for (int j = 0; j < 8; ++j) t[j] = f2bfh(((float)v0[j] + (float)v1[j]) * rv);
        *(bf16x8*)&Alds[row][k8] = t;
    }
    __syncthreads();

    f32x4 acc[4][4];
    #pragma unroll
    for (int r = 0; r < 4; ++r)
        #pragma unroll
        for (int c = 0; c < 4; ++c) acc[r][c] = (f32x4){0.f, 0.f, 0.f, 0.f};

    const int wcol = wave * 64;
    #pragma unroll
    for (int kk = 0; kk < 16; ++kk) {
        bf16x8 a[4];
        #pragma unroll
        for (int r = 0; r < 4; ++r)
            a[r] = *(const bf16x8*)&Alds[r * 16 + col][kk * 32 + quad * 8];
        #pragma unroll
        for (int c = 0; c < 4; ++c) {
            bf16x8 b = *(const bf16x8*)&Wb[(size_t)(wcol + c * 16 + col) * 512
                                           + kk * 32 + quad * 8];
            #pragma unroll
            for (int r = 0; r < 4; ++r)
                acc[r][c] = mfma16(a[r], b, acc[r][c]);
        }
    }

    #pragma unroll
    for (int r = 0; r < 4; ++r)
        #pragma unroll
        for (int c = 0; c < 4; ++c)
            #pragma unroll
            for (int g = 0; g < 4; ++g) {
                int m = mblk + r * 16 + quad * 4 + g;
                int n = wcol + c * 16 + col;
                float v = acc[r][c][g] + bf2f(bb[n]);
                if (f32) ((float*)Out)[(size_t)m * DIM + n] = v;
                else     ((ushort_t*)Out)[(size_t)m * DIM + n] = f2bf(v);
            }
}

// ---------------------------------------------------------------------------
// Fallback kernels (R13-proven) for smaller workspaces.
// ---------------------------------------------------------------------------
__global__ __launch_bounds__(256)
void transpose_kernel(const int* __restrict__ flag, const void* __restrict__ emb,
                      ushort_t* __restrict__ embT)
{
    __shared__ float tile[64][65];
    const bool f32 = (*flag == 0);
    const int t  = threadIdx.x;
    const int j0 = blockIdx.x * 64;
    const int d0 = blockIdx.y * 64;
    {
        int r = t >> 2, cs = (t & 3) * 16;
        if (f32) {
            const float* src = (const float*)emb + (size_t)(j0 + r) * DIM + d0 + cs;
            #pragma unroll
            for (int i = 0; i < 16; i += 4) {
                float4 v = *(const float4*)(src + i);
                tile[r][cs + i]     = v.x;
                tile[r][cs + i + 1] = v.y;
                tile[r][cs + i + 2] = v.z;
                tile[r][cs + i + 3] = v.w;
            }
        } else {
            const ushort_t* src = (const ushort_t*)emb + (size_t)(j0 + r) * DIM + d0 + cs;
            #pragma unroll
            for (int i = 0; i < 16; ++i) tile[r][cs + i] = bf2f(src[i]);
        }
    }
    __syncthreads();
    {
        int d = t >> 2, js = (t & 3) * 16;
        ushort_t buf[16];
        #pragma unroll
        for (int i = 0; i < 16; ++i) buf[i] = f2bf(tile[js + i][d]);
        ushort_t* dst = embT + (size_t)(d0 + d) * NTOK + j0 + js;
        *(uint4*)dst       = *(uint4*)&buf[0];
        *(uint4*)(dst + 8) = *(uint4*)&buf[8];
    }
}

__global__ __launch_bounds__(512)
void projq_kernel(const int* __restrict__ flag, const void* __restrict__ emb,
                  const void* __restrict__ W, const void* __restrict__ bias,
                  ushort_t* __restrict__ C)
{
    __shared__ ushort_t Alds[32][LDA];
    const bool f32 = (*flag == 0);
    const int tid  = threadIdx.x;
    const int wave = tid >> 6;
    const int lane = tid & 63;
    const int quad = lane >> 4;
    const int col  = lane & 15;
    const int mblk = blockIdx.x * 32;

    #pragma unroll
    for (int i = 0; i < 4; ++i) {
        int chunk = i * 512 + tid;
        int row = chunk >> 6;
        int k8  = (chunk & 63) * 8;
        *(bf16x8*)&Alds[row][k8] = load8(emb, (size_t)(mblk + row) * 512 + k8, f32);
    }
    __syncthreads();

    f32x4 acc[2][4];
    #pragma unroll
    for (int r = 0; r < 2; ++r)
        #pragma unroll
        for (int c = 0; c < 4; ++c) acc[r][c] = (f32x4){0.f, 0.f, 0.f, 0.f};

    const int wcol = wave * 64;
    #pragma unroll
    for (int kk = 0; kk < 16; ++kk) {
        bf16x8 a0 = *(const bf16x8*)&Alds[col][kk * 32 + quad * 8];
        bf16x8 a1 = *(const bf16x8*)&Alds[16 + col][kk * 32 + quad * 8];
        #pragma unroll
        for (int c = 0; c < 4; ++c) {
            bf16x8 b = load8(W, (size_t)(wcol + c * 16 + col) * 512 + kk * 32 + quad * 8, f32);
            acc[0][c] = mfma16(a0, b, acc[0][c]);
            acc[1][c] = mfma16(a1, b, acc[1][c]);
        }
    }

    #pragma unroll
    for (int r = 0; r < 2; ++r)
        #pragma unroll
        for (int c = 0; c < 4; ++c)
            #pragma unroll
            for (int g = 0; g < 4; ++g) {
                int m = mblk + r * 16 + quad * 4 + g;
                int n = wcol + c * 16 + col;
                C[(size_t)m * DIM + n] = f2bf(acc[r][c][g] + loadS(bias, n, f32));
            }
}

template <int VT>
__global__ __launch_bounds__(1024)
void attn_fused_kernel(const int* __restrict__ flag, const ushort_t* __restrict__ Q,
                       const void* __restrict__ embOrT, const void* __restrict__ Wv,
                       const void* __restrict__ bv, void* __restrict__ Out)
{
    __shared__ ushort_t Qlds[32][LDA];
    __shared__ ushort_t Plds[2][32][LDP];
    __shared__ float    Lpart[16][32];

    const bool f32 = (*flag == 0);
    const int tid  = threadIdx.x;
    const int wave = tid >> 6;
    const int lane = tid & 63;
    const int quad = lane >> 4;
    const int col  = lane & 15;
    const int q0   = blockIdx.x * 32;

    #pragma unroll
    for (int i = 0; i < 2; ++i) {
        int chunk = i * 1024 + tid;
        int row = chunk >> 6;
        int k8  = (chunk & 63) * 8;
        *(bf16x8*)&Qlds[row][k8] = *(const bf16x8*)&Q[(size_t)(q0 + row) * 512 + k8];
    }
    __syncthreads();

    f32x4 accO[2][2];
    #pragma unroll
    for (int r = 0; r < 2; ++r)
        #pragma unroll
        for (int c = 0; c < 2; ++c) accO[r][c] = (f32x4){0.f, 0.f, 0.f, 0.f};

    float lsum[2][4];
    #pragma unroll
    for (int r = 0; r < 2; ++r)
        #pragma unroll
        for (int g = 0; g < 4; ++g) lsum[r][g] = 0.f;

    const float sc = 0.04419417382415922f * 1.4426950408889634f;
    const int wOcol = wave * 32;

    for (int it = 0; it < 32; ++it) {
        const int j0  = it * 256;
        const int buf = it & 1;

        bf16x8 kb[16];
        const size_t keyrow = (size_t)(j0 + wave * 16 + col) * 512;
        #pragma unroll
        for (int kk = 0; kk < 16; ++kk)
            kb[kk] = *(const bf16x8*)&Q[keyrow + kk * 32 + quad * 8];

        f32x4 accS[2];
        accS[0] = (f32x4){0.f, 0.f, 0.f, 0.f};
        accS[1] = (f32x4){0.f, 0.f, 0.f, 0.f};
        #pragma unroll
        for (int kk = 0; kk < 16; ++kk) {
            bf16x8 a0 = *(const bf16x8*)&Qlds[col][kk * 32 + quad * 8];
            bf16x8 a1 = *(const bf16x8*)&Qlds[16 + col][kk * 32 + quad * 8];
            accS[0] = mfma16(a0, kb[kk], accS[0]);
            accS[1] = mfma16(a1, kb[kk], accS[1]);
        }

        bf16x8 vb[16];
        #pragma unroll
        for (int kk = 0; kk < 8; ++kk)
            #pragma unroll
            for (int c = 0; c < 2; ++c) {
                if (VT) {
                    vb[kk * 2 + c] = *(const bf16x8*)((const ushort_t*)embOrT
                        + (size_t)(wOcol + c * 16 + col) * NTOK + j0 + kk * 32 + quad * 8);
                } else {
                    size_t base = (size_t)(j0 + kk * 32 + quad * 8) * 512 + (wOcol + c * 16 + col);
                    bf16x8 b;
                    if (f32) {
                        const float* bp = (const float*)embOrT + base;
                        #pragma unroll
                        for (int j = 0; j < 8; ++j) b[j] = f2bfh(bp[(size_t)j * 512]);
                    } else {
                        const __bf16* bp = (const __bf16*)embOrT + base;
                        #pragma unroll
                        for (int j = 0; j < 8; ++j) b[j] = bp[(size_t)j * 512];
                    }
                    vb[kk * 2 + c] = b;
                }
            }

        #pragma unroll
        for (int r = 0; r < 2; ++r)
            #pragma unroll
            for (int g = 0; g < 4; ++g) {
                float p = exp2f(fminf(accS[r][g] * sc, 126.0f));
                lsum[r][g] += p;
                Plds[buf][r * 16 + quad * 4 + g][wave * 16 + col] = f2bf(p);
            }

        __syncthreads();

        #pragma unroll
        for (int kk = 0; kk < 8; ++kk) {
            bf16x8 a0 = *(const bf16x8*)&Plds[buf][col][kk * 32 + quad * 8];
            bf16x8 a1 = *(const bf16x8*)&Plds[buf][16 + col][kk * 32 + quad * 8];
            #pragma unroll
            for (int c = 0; c < 2; ++c) {
                accO[0][c] = mfma16(a0, vb[kk * 2 + c], accO[0][c]);
                accO[1][c] = mfma16(a1, vb[kk * 2 + c], accO[1][c]);
            }
        }
    }

    #pragma unroll
    for (int r = 0; r < 2; ++r)
        #pragma unroll
        for (int g = 0; g < 4; ++g) {
            float s = lsum[r][g];
            s += __shfl_xor(s, 1);
            s += __shfl_xor(s, 2);
            s += __shfl_xor(s, 4);
            s += __shfl_xor(s, 8);
            lsum[r][g] = s;
        }
    if (col == 0) {
        #pragma unroll
        for (int r = 0; r < 2; ++r)
            #pragma unroll
            for (int g = 0; g < 4; ++g)
                Lpart[wave][r * 16 + quad * 4 + g] = lsum[r][g];
    }
    __syncthreads();

    #pragma unroll
    for (int r = 0; r < 2; ++r) {
        float rinv[4];
        #pragma unroll
        for (int g = 0; g < 4; ++g) {
            float t = 0.f;
            #pragma unroll
            for (int w = 0; w < 16; ++w) t += Lpart[w][r * 16 + quad * 4 + g];
            rinv[g] = 1.0f / t;
        }
        #pragma unroll
        for (int c = 0; c < 2; ++c)
            #pragma unroll
            for (int g = 0; g < 4; ++g)
                Qlds[r * 16 + quad * 4 + g][wOcol + c * 16 + col] = f2bf(accO[r][c][g] * rinv[g]);
    }
    __syncthreads();

    f32x4 acc2[2][2];
    #pragma unroll
    for (int r = 0; r < 2; ++r)
        #pragma unroll
        for (int c = 0; c < 2; ++c) acc2[r][c] = (f32x4){0.f, 0.f, 0.f, 0.f};

    #pragma unroll
    for (int kk = 0; kk < 16; ++kk) {
        bf16x8 a0 = *(const bf16x8*)&Qlds[col][kk * 32 + quad * 8];
        bf16x8 a1 = *(const bf16x8*)&Qlds[16 + col][kk * 32 + quad * 8];
        #pragma unroll
        for (int c = 0; c < 2; ++c) {
            bf16x8 b = load8(Wv, (size_t)(wOcol + c * 16 + col) * 512 + kk * 32 + quad * 8, f32);
            acc2[0][c] = mfma16(a0, b, acc2[0][c]);
            acc2[1][c] = mfma16(a1, b, acc2[1][c]);
        }
    }

    #pragma unroll
    for (int r = 0; r < 2; ++r)
        #pragma unroll
        for (int c = 0; c < 2; ++c)
            #pragma unroll
            for (int g = 0; g < 4; ++g) {
                int m = q0 + r * 16 + quad * 4 + g;
                int n = wOcol + c * 16 + col;
                float v = acc2[r][c][g] + loadS(bv, n, f32);
                if (f32) ((float*)Out)[(size_t)m * DIM + n] = v;
                else     ((ushort_t*)Out)[(size_t)m * DIM + n] = f2bf(v);
            }
}

extern "C" void kernel_launch(void* const* d_in, const int* in_sizes, int n_in,
                              void* d_out, int out_size, void* d_ws, size_t ws_size,
                              hipStream_t stream)
{
    const void* emb = d_in[0];
    const void* Wqk = d_in[1];
    const void* bqk = d_in[2];
    const void* Wv  = d_in[3];
    const void* bv  = d_in[4];

    char* W = (char*)d_ws;
    int* flag = (int*)W;

    // New (R16) layout: flag | lsum4 (128KB) | Wqkb | Wvb | bqkb | bvb | embT | Qws | P[4]
    const size_t needC = 64 + 4 * (size_t)NTOK * 4 + 2 * (size_t)DIM * DIM * 2
                       + 2 * DIM * 2 + 6 * (size_t)NTOK * DIM * 2;   // ~49.1 MB
    // Old (R14) layout
    const size_t needA = 64 + 65536 + 2 * (size_t)DIM * DIM * 2 + 2 * DIM * 2
                       + 4 * (size_t)NTOK * DIM * 2;                  // ~33.1 MB
    const size_t needB = 64 + 2 * (size_t)NTOK * DIM * 2;             // 16.03 MB

    detect_kernel<<<dim3(1), dim3(64), 0, stream>>>((const ushort_t*)emb, flag);

    if (ws_size >= needC) {
        float*    lsum4 = (float*)(W + 64);                          // 128 KB
        ushort_t* Wqkb  = (ushort_t*)(W + 64 + 4 * (size_t)NTOK * 4);
        ushort_t* Wvb   = Wqkb + (size_t)DIM * DIM;
        ushort_t* bqkb  = Wvb + (size_t)DIM * DIM;
        ushort_t* bvb   = bqkb + DIM;
        ushort_t* embT  = bvb + DIM;                                 // 8 MB
        ushort_t* Qws   = embT + (size_t)DIM * NTOK;                 // 8 MB
        ushort_t* P4    = Qws + (size_t)DIM * NTOK;                  // 4 x 8 MB

        prep_kernel<<<dim3(128), dim3(256), 0, stream>>>(flag, Wqk, bqk, Wv, bv,
                                                         Wqkb, bqkb, Wvb, bvb);
        projqT_kernel<<<dim3(NTOK / 64), dim3(512), 0, stream>>>(flag, emb, Wqkb, bqkb,
                                                                 Qws, embT);
        attn128_kernel<<<dim3(256), dim3(1024), 0, stream>>>(Qws, embT, P4, lsum4);
        finalize4_kernel<<<dim3(NTOK / 64), dim3(512), 0, stream>>>(flag, P4, lsum4,
                                                                    Wvb, bvb, d_out);
    } else if (ws_size >= needA) {
        float*    lsumA = (float*)(W + 64);                          // 64 KB
        ushort_t* Wqkb  = (ushort_t*)(W + 64 + 65536);
        ushort_t* Wvb   = Wqkb + (size_t)DIM * DIM;
        ushort_t* bqkb  = Wvb + (size_t)DIM * DIM;
        ushort_t* bvb   = bqkb + DIM;
        ushort_t* embT  = bvb + DIM;
        ushort_t* Qws   = embT + (size_t)DIM * NTOK;
        ushort_t* P0    = Qws + (size_t)DIM * NTOK;
        ushort_t* P1    = P0 + (size_t)NTOK * DIM;

        prep_kernel<<<dim3(128), dim3(256), 0, stream>>>(flag, Wqk, bqk, Wv, bv,
                                                         Wqkb, bqkb, Wvb, bvb);
        projqT_kernel<<<dim3(NTOK / 64), dim3(512), 0, stream>>>(flag, emb, Wqkb, bqkb,
                                                                 Qws, embT);
        attn64_kernel<<<dim3(256), dim3(1024), 0, stream>>>(Qws, embT, P0, P1, lsumA);
        finalize_kernel<<<dim3(NTOK / 64), dim3(512), 0, stream>>>(flag, P0, P1, lsumA,
                                                                   Wvb, bvb, d_out);
    } else if (ws_size >= needB) {
        ushort_t* embT2 = (ushort_t*)(W + 64);
        ushort_t* Qws2  = embT2 + (size_t)DIM * NTOK;
        transpose_kernel<<<dim3(128, 8), dim3(256), 0, stream>>>(flag, emb, embT2);
        projq_kernel<<<dim3(NTOK / 32), dim3(512), 0, stream>>>(flag, emb, Wqk, bqk, Qws2);
        attn_fused_kernel<1><<<dim3(NTOK / 32), dim3(1024), 0, stream>>>(
            flag, Qws2, embT2, Wv, bv, d_out);
    } else {
        ushort_t* Qsm = (ushort_t*)(W + 64);
        projq_kernel<<<dim3(NTOK / 32), dim3(512), 0, stream>>>(flag, emb, Wqk, bqk, Qsm);
        attn_fused_kernel<0><<<dim3(NTOK / 32), dim3(1024), 0, stream>>>(
            flag, Qsm, emb, Wv, bv, d_out);
    }
}

// Round 3
// 316.519 us; speedup vs baseline: 2.0274x; 1.3933x over previous
//
#include <hip/hip_runtime.h>
#include <hip/hip_bf16.h>

// N=8192, D=512.  Q = emb@Wqk^T+bqk (K==Q); out = softmax(QK^T/sqrt(512)) @ V.
// Softmax rows sum to 1 => out = (softmax(S)@emb) @ Wv^T + bv (V never built).
// R17: v2 (337us) was LDS-A-read bound (one Qlds read per S-MFMA, 512KB/iter/CU,
// +2.5e7 bank conflicts). v3 = m214-attn recipe: 8 waves x 256-reg budget,
// Q-fragments in registers (wave owns 16 rows, A-reads eliminated), K double-
// buffered in LDS via global_load_lds (zero staging VGPRs) with XOR swizzle
// (byte ^= (row&7)<<4, both-sides), counted vmcnt(8) never drained mid-loop,
// P 16KB swizzled, vb in 2 kslot passes (16 regs). Budget: qf 64 + accO 128
// + lsum 4 persistent, ~40 transient -> ~240 < 256 cap (launch_bounds(512,2)).
// R15's spill came from 290-reg demand; this is the trimmed version.
// Fallbacks (attn64 etc.) unchanged.

#define NTOK 8192
#define DIM  512

typedef unsigned short ushort_t;
typedef unsigned int u32;
typedef __attribute__((ext_vector_type(8))) __bf16 bf16x8;
typedef __attribute__((ext_vector_type(4))) float f32x4;

__device__ __forceinline__ float bf2f(ushort_t u) {
    union { unsigned int i; float f; } v; v.i = ((unsigned int)u) << 16; return v.f;
}
__device__ __forceinline__ ushort_t f2bf(float f) {
    union { float f; unsigned int i; } v; v.f = f;
    unsigned int b = v.i;
    return (ushort_t)((b + 0x7FFFu + ((b >> 16) & 1u)) >> 16);   // RNE
}
__device__ __forceinline__ __bf16 f2bfh(float f) {
    union { ushort_t u; __bf16 h; } c; c.u = f2bf(f); return c.h;
}
__device__ __forceinline__ f32x4 mfma16(bf16x8 a, bf16x8 b, f32x4 c) {
    return __builtin_amdgcn_mfma_f32_16x16x32_bf16(a, b, c, 0, 0, 0);
}
__device__ __forceinline__ bf16x8 load8(const void* p, size_t idx, bool f32) {
    if (f32) {
        const float* f = (const float*)p + idx;
        bf16x8 r;
        #pragma unroll
        for (int j = 0; j < 8; ++j) r[j] = f2bfh(f[j]);
        return r;
    }
    return *(const bf16x8*)((const ushort_t*)p + idx);
}
__device__ __forceinline__ float loadS(const void* p, size_t idx, bool f32) {
    return f32 ? ((const float*)p)[idx] : bf2f(((const ushort_t*)p)[idx]);
}
__device__ __forceinline__ void gload_lds16(const ushort_t* g, ushort_t* l) {
    __builtin_amdgcn_global_load_lds(
        (const __attribute__((address_space(1))) u32*)g,
        (__attribute__((address_space(3))) u32*)l, 16, 0, 0);
}

#define LDA 520   // 260 dw, %32=4: uniform bank spread for b128 row reads
#define LDP 264

// ---------------------------------------------------------------------------
// Dtype probe: flag=1 => bf16 data, flag=0 => fp32.
// ---------------------------------------------------------------------------
__global__ void detect_kernel(const ushort_t* __restrict__ emb, int* __restrict__ flag)
{
    int lane = threadIdx.x;
    int cnt = 0;
    #pragma unroll
    for (int i = 0; i < 8; ++i) {
        ushort_t u = emb[(size_t)(lane * 8 + i) * 2];
        int a = u & 0x7FFF;
        int e = (u >> 7) & 0xFF;
        if (a == 0 || (e >= 111 && e <= 143)) cnt++;
    }
    cnt += __shfl_xor(cnt, 1);  cnt += __shfl_xor(cnt, 2);  cnt += __shfl_xor(cnt, 4);
    cnt += __shfl_xor(cnt, 8);  cnt += __shfl_xor(cnt, 16); cnt += __shfl_xor(cnt, 32);
    if (lane == 0) *flag = (cnt >= 460) ? 1 : 0;
}

// ---------------------------------------------------------------------------
// Prep: convert Wqk, Wv (512x512) + bqk, bv (512) to bf16 in ws.
// ---------------------------------------------------------------------------
__global__ __launch_bounds__(256)
void prep_kernel(const int* __restrict__ flag,
                 const void* __restrict__ Wqk, const void* __restrict__ bqk,
                 const void* __restrict__ Wv,  const void* __restrict__ bv,
                 ushort_t* __restrict__ Wqkb, ushort_t* __restrict__ bqkb,
                 ushort_t* __restrict__ Wvb,  ushort_t* __restrict__ bvb)
{
    const bool f32 = (*flag == 0);
    size_t gid = (size_t)blockIdx.x * 256 + threadIdx.x;   // 32768 threads
    size_t base = gid * 8;                                  // 262144 = 512*512
    *(bf16x8*)&Wqkb[base] = load8(Wqk, base, f32);
    *(bf16x8*)&Wvb[base]  = load8(Wv,  base, f32);
    if (gid < 64) {
        *(bf16x8*)&bqkb[base] = load8(bqk, base, f32);
        *(bf16x8*)&bvb[base]  = load8(bv,  base, f32);
    }
}

// ---------------------------------------------------------------------------
// Fused: Q[64 rows] = emb@Wqk^T+bqk AND embT columns, from one staged tile.
// ---------------------------------------------------------------------------
__global__ __launch_bounds__(512)
void projqT_kernel(const int* __restrict__ flag, const void* __restrict__ emb,
                   const ushort_t* __restrict__ Wb, const ushort_t* __restrict__ bb,
                   ushort_t* __restrict__ C, ushort_t* __restrict__ embT)
{
    __shared__ ushort_t Alds[64][LDA];   // 66,560 B
    const bool f32 = (*flag == 0);
    const int tid  = threadIdx.x;
    const int wave = tid >> 6;
    const int lane = tid & 63;
    const int quad = lane >> 4;
    const int col  = lane & 15;
    const int mblk = blockIdx.x * 64;

    #pragma unroll
    for (int i = 0; i < 8; ++i) {
        int chunk = i * 512 + tid;
        int row = chunk >> 6;
        int k8  = (chunk & 63) * 8;
        *(bf16x8*)&Alds[row][k8] = load8(emb, (size_t)(mblk + row) * 512 + k8, f32);
    }
    __syncthreads();

    // ---- transpose store: thread t owns dim t, 64 tokens (128 B) ----
    {
        ushort_t buf[64];
        #pragma unroll
        for (int r = 0; r < 64; ++r) buf[r] = Alds[r][tid];
        ushort_t* dst = embT + (size_t)tid * NTOK + mblk;
        #pragma unroll
        for (int i = 0; i < 8; ++i)
            *(uint4*)(dst + i * 8) = *(uint4*)&buf[i * 8];
    }

    // ---- Q projection (64 rows x this wave's 64 cols) ----
    f32x4 acc[4][4];
    #pragma unroll
    for (int r = 0; r < 4; ++r)
        #pragma unroll
        for (int c = 0; c < 4; ++c) acc[r][c] = (f32x4){0.f, 0.f, 0.f, 0.f};

    const int wcol = wave * 64;
    #pragma unroll
    for (int kk = 0; kk < 16; ++kk) {
        bf16x8 a[4];
        #pragma unroll
        for (int r = 0; r < 4; ++r)
            a[r] = *(const bf16x8*)&Alds[r * 16 + col][kk * 32 + quad * 8];
        #pragma unroll
        for (int c = 0; c < 4; ++c) {
            bf16x8 b = *(const bf16x8*)&Wb[(size_t)(wcol + c * 16 + col) * 512
                                           + kk * 32 + quad * 8];
            #pragma unroll
            for (int r = 0; r < 4; ++r)
                acc[r][c] = mfma16(a[r], b, acc[r][c]);
        }
    }

    #pragma unroll
    for (int r = 0; r < 4; ++r)
        #pragma unroll
        for (int c = 0; c < 4; ++c)
            #pragma unroll
            for (int g = 0; g < 4; ++g) {
                int m = mblk + r * 16 + quad * 4 + g;
                int n = wcol + c * 16 + col;
                C[(size_t)m * DIM + n] = f2bf(acc[r][c][g] + bf2f(bb[n]));
            }
}

// ---------------------------------------------------------------------------
// attn128 v3 (R17): 256 blocks = 64 q-tiles (Tq=128) x 4 key-quarters,
// 512 thr = 8 waves, 2 waves/SIMD with ~240-reg budget.
// Wave w: S-phase owns rows [q0+16w,+16) (Q in 64 VGPRs) x all 64 keys/iter;
// PV-phase owns dims [64w,+64), accO[8][4] (128 AGPR).
// K: LDS double-buffer (2x64KB), staged via global_load_lds with pre-swizzled
// source (byte ^= (row&7)<<4), counted vmcnt(8) across barriers.
// P: 16KB LDS, same XOR swizzle. 2 barriers/iter (top barrier = P fence).
// ---------------------------------------------------------------------------
#define QT2  128
#define KT2  64
#define NIT2 32

__global__ __launch_bounds__(512, 2)
void attn128_kernel(const ushort_t* __restrict__ Q, const ushort_t* __restrict__ embT,
                    ushort_t* __restrict__ P, float* __restrict__ lsumA)
{
    __shared__ ushort_t Klds[2][KT2 * DIM];   // 131,072 B
    __shared__ ushort_t Plds[QT2 * KT2];      //  16,384 B (147,456 total)

    const int tid  = threadIdx.x;
    const int wave = tid >> 6;
    const int lane = tid & 63;
    const int quad = lane >> 4;
    const int col  = lane & 15;
    const int qt   = blockIdx.x & 63;
    const int ks   = blockIdx.x >> 6;           // 0..3 key quarter
    const int q0   = qt * QT2;
    const int kbase = ks * (NTOK / 4);
    ushort_t* Ps = P + (size_t)ks * NTOK * DIM;

    // Swizzle constants. All swizzled rows used below have (row&7)==(col&7)
    // (K reads row=kt*16+col; P reads row=rt*16+col), except P writes which
    // compute their own row parity inline.
    const int s3 = col & 7;
    const int qo = (quad ^ (s3 & 3)) << 4;    // byte bits 4-5
    const int kx = (s3 >> 2) << 6;            // byte bit 6

    // ---- Q fragments: wave owns rows [q0+16w, +16), full K=512 (64 VGPR) ----
    bf16x8 qf[16];
    {
        const ushort_t* qrow = Q + (size_t)(q0 + wave * 16 + col) * DIM + quad * 8;
        #pragma unroll
        for (int kk = 0; kk < 16; ++kk)
            qf[kk] = *(const bf16x8*)(qrow + kk * 32);
    }

    // K-read byte bases per key-tile: row*1024 | qo, ^ kx (disjoint bit fields)
    int rbk[4];
    #pragma unroll
    for (int kt = 0; kt < 4; ++kt)
        rbk[kt] = (((kt * 16 + col) << 10) | qo) ^ kx;

    const int pwrow = wave * 16 + quad * 4;          // P-write row base (+g)
    const int pb    = ((col << 7) | qo) ^ kx;        // PV-read byte base

    // ---- stage K(0) into buf 0: wave stages rows [8w,8w+8); source lane-XOR'd
    //      so linear LDS holds row-swizzled content ----
    {
        const size_t gb = (size_t)kbase * DIM;
        #pragma unroll
        for (int i = 0; i < 8; ++i) {
            const int r = wave * 8 + i;
            gload_lds16(Q + gb + (size_t)r * DIM + ((lane ^ (r & 7)) << 3),
                        &Klds[0][r * DIM]);
        }
    }

    f32x4 accO[8][4];
    #pragma unroll
    for (int r = 0; r < 8; ++r)
        #pragma unroll
        for (int c = 0; c < 4; ++c) accO[r][c] = (f32x4){0.f, 0.f, 0.f, 0.f};
    float lsum[4] = {0.f, 0.f, 0.f, 0.f};

    const float sc = 0.04419417382415922f * 1.4426950408889634f;  // 1/sqrt(512)*log2e
    const int wd = wave * 64;

    for (int it = 0; it < NIT2; ++it) {
        const int cur = it & 1;
        const char* Kc = (const char*)&Klds[cur][0];
        const int j0 = kbase + it * KT2;

        // ---- prefetch K(t+1); counted vmcnt: wait only for K(t)'s 8 loads ----
        if (it + 1 < NIT2) {
            const size_t gb = (size_t)(j0 + KT2) * DIM;
            ushort_t* dst = &Klds[cur ^ 1][0];
            #pragma unroll
            for (int i = 0; i < 8; ++i) {
                const int r = wave * 8 + i;
                gload_lds16(Q + gb + (size_t)r * DIM + ((lane ^ (r & 7)) << 3),
                            dst + r * DIM);
            }
            asm volatile("s_waitcnt vmcnt(8)" ::: "memory");
        } else {
            asm volatile("s_waitcnt vmcnt(0)" ::: "memory");
        }
        // Top barrier: K(t) staged by all waves AND all waves done with P(t-1)
        __builtin_amdgcn_s_barrier();

        // ---- S = Q(wave's 16 rows) @ K(all 64 keys)^T, A from registers ----
        f32x4 accS[4];
        #pragma unroll
        for (int kt = 0; kt < 4; ++kt) accS[kt] = (f32x4){0.f, 0.f, 0.f, 0.f};
        __builtin_amdgcn_s_setprio(1);
        #pragma unroll
        for (int kk = 0; kk < 16; ++kk)
            #pragma unroll
            for (int kt = 0; kt < 4; ++kt) {
                bf16x8 kb = *(const bf16x8*)(Kc + (rbk[kt] ^ (kk << 6)));
                accS[kt] = mfma16(qf[kk], kb, accS[kt]);
            }
        __builtin_amdgcn_s_setprio(0);

        // ---- P = exp2(S*sc) -> swizzled Plds; row sums (rows wave-owned) ----
        #pragma unroll
        for (int kt = 0; kt < 4; ++kt)
            #pragma unroll
            for (int g = 0; g < 4; ++g) {
                float p = exp2f(fminf(accS[kt][g] * sc, 126.0f));
                lsum[g] += p;
                const int prow = pwrow + g;
                Plds[(prow << 6) | ((kt * 16 + col) ^ ((prow & 7) << 3))] = f2bf(p);
            }

        // ---- vb kslot 0 (global; latency hidden under exp + barrier) ----
        const ushort_t* eb = embT + (size_t)(wd + col) * NTOK + j0 + quad * 8;
        bf16x8 vb0[4];
        #pragma unroll
        for (int dt = 0; dt < 4; ++dt)
            vb0[dt] = *(const bf16x8*)(eb + (size_t)(dt * 16) * NTOK);

        // ---- B1: P visible (LDS only; K-prefetch stays in flight) ----
        asm volatile("s_waitcnt lgkmcnt(0)" ::: "memory");
        __builtin_amdgcn_s_barrier();

        // ---- PV kslot 0: O += P[:, 0:32] @ embT[:, 0:32]^T ----
        __builtin_amdgcn_s_setprio(1);
        #pragma unroll
        for (int rt = 0; rt < 8; ++rt) {
            bf16x8 pa = *(const bf16x8*)((const char*)Plds + (rt * 2048 + pb));
            #pragma unroll
            for (int dt = 0; dt < 4; ++dt)
                accO[rt][dt] = mfma16(pa, vb0[dt], accO[rt][dt]);
        }
        __builtin_amdgcn_s_setprio(0);

        // ---- vb kslot 1 + PV kslot 1 ----
        bf16x8 vb1[4];
        #pragma unroll
        for (int dt = 0; dt < 4; ++dt)
            vb1[dt] = *(const bf16x8*)(eb + (size_t)(dt * 16) * NTOK + 32);

        __builtin_amdgcn_s_setprio(1);
        #pragma unroll
        for (int rt = 0; rt < 8; ++rt) {
            bf16x8 pa = *(const bf16x8*)((const char*)Plds + (rt * 2048 + (pb ^ 64)));
            #pragma unroll
            for (int dt = 0; dt < 4; ++dt)
                accO[rt][dt] = mfma16(pa, vb1[dt], accO[rt][dt]);
        }
        __builtin_amdgcn_s_setprio(0);
        // No end barrier: next iter's top barrier fences P(t) reads vs P(t+1)
        // writes, and K(t+2) staging is issued after it.
    }

    // ---- row sums: reduce over col lanes (keys); rows wave-owned ----
    #pragma unroll
    for (int g = 0; g < 4; ++g) {
        float s = lsum[g];
        s += __shfl_xor(s, 1);
        s += __shfl_xor(s, 2);
        s += __shfl_xor(s, 4);
        s += __shfl_xor(s, 8);
        if (col == 0)
            lsumA[(size_t)ks * NTOK + q0 + pwrow + g] = s;
    }

    // ---- store O partial (pre-normalization) ----
    #pragma unroll
    for (int rt = 0; rt < 8; ++rt)
        #pragma unroll
        for (int dt = 0; dt < 4; ++dt)
            #pragma unroll
            for (int g = 0; g < 4; ++g)
                Ps[(size_t)(q0 + rt * 16 + quad * 4 + g) * DIM + wd + dt * 16 + col]
                    = f2bf(accO[rt][dt][g]);
}

// ---------------------------------------------------------------------------
// Finalize4: T = (P0+P1+P2+P3)/(l0+l1+l2+l3), out = T @ Wv^T + bv.
// ---------------------------------------------------------------------------
__global__ __launch_bounds__(512)
void finalize4_kernel(const int* __restrict__ flag,
                      const ushort_t* __restrict__ P, const float* __restrict__ lsumA,
                      const ushort_t* __restrict__ Wb, const ushort_t* __restrict__ bb,
                      void* __restrict__ Out)
{
    __shared__ ushort_t Alds[64][LDA];
    const bool f32 = (*flag == 0);
    const int tid  = threadIdx.x;
    const int wave = tid >> 6;
    const int lane = tid & 63;
    const int quad = lane >> 4;
    const int col  = lane & 15;
    const int mblk = blockIdx.x * 64;
    const size_t PSZ = (size_t)NTOK * DIM;

    #pragma unroll
    for (int i = 0; i < 8; ++i) {
        int chunk = i * 512 + tid;
        int row = chunk >> 6;
        int k8  = (chunk & 63) * 8;
        int m   = mblk + row;
        float rv = 1.0f / (lsumA[m] + lsumA[NTOK + m]
                         + lsumA[2 * NTOK + m] + lsumA[3 * NTOK + m]);
        size_t off = (size_t)m * 512 + k8;
        bf16x8 v0 = *(const bf16x8*)&P[off];
        bf16x8 v1 = *(const bf16x8*)&P[PSZ + off];
        bf16x8 v2 = *(const bf16x8*)&P[2 * PSZ + off];
        bf16x8 v3 = *(const bf16x8*)&P[3 * PSZ + off];
        bf16x8 t;
        #pragma unroll
        for (int j = 0; j < 8; ++j)
            t[j] = f2bfh(((float)v0[j] + (float)v1[j] + (float)v2[j] + (float)v3[j]) * rv);
        *(bf16x8*)&Alds[row][k8] = t;
    }
    __syncthreads();

    f32x4 acc[4][4];
    #pragma unroll
    for (int r = 0; r < 4; ++r)
        #pragma unroll
        for (int c = 0; c < 4; ++c) acc[r][c] = (f32x4){0.f, 0.f, 0.f, 0.f};

    const int wcol = wave * 64;
    #pragma unroll
    for (int kk = 0; kk < 16; ++kk) {
        bf16x8 a[4];
        #pragma unroll
        for (int r = 0; r < 4; ++r)
            a[r] = *(const bf16x8*)&Alds[r * 16 + col][kk * 32 + quad * 8];
        #pragma unroll
        for (int c = 0; c < 4; ++c) {
            bf16x8 b = *(const bf16x8*)&Wb[(size_t)(wcol + c * 16 + col) * 512
                                           + kk * 32 + quad * 8];
            #pragma unroll
            for (int r = 0; r < 4; ++r)
                acc[r][c] = mfma16(a[r], b, acc[r][c]);
        }
    }

    #pragma unroll
    for (int r = 0; r < 4; ++r)
        #pragma unroll
        for (int c = 0; c < 4; ++c)
            #pragma unroll
            for (int g = 0; g < 4; ++g) {
                int m = mblk + r * 16 + quad * 4 + g;
                int n = wcol + c * 16 + col;
                float v = acc[r][c][g] + bf2f(bb[n]);
                if (f32) ((float*)Out)[(size_t)m * DIM + n] = v;
                else     ((ushort_t*)Out)[(size_t)m * DIM + n] = f2bf(v);
            }
}

// ---------------------------------------------------------------------------
// R13-proven attn64 + finalize (fallback for mid-size workspace).
// ---------------------------------------------------------------------------
__global__ __launch_bounds__(1024)
void attn64_kernel(const ushort_t* __restrict__ Q, const ushort_t* __restrict__ embT,
                   ushort_t* __restrict__ P0, ushort_t* __restrict__ P1,
                   float* __restrict__ lsumA)
{
    __shared__ ushort_t Qlds[64][LDA];
    __shared__ ushort_t Plds[2][64][LDP];
    __shared__ float    Lp[16][64];

    const int tid  = threadIdx.x;
    const int wave = tid >> 6;
    const int lane = tid & 63;
    const int quad = lane >> 4;
    const int col  = lane & 15;
    const int qt   = blockIdx.x & 127;
    const int ks   = blockIdx.x >> 7;
    const int q0   = qt * 64;
    const int kbase = ks * 4096;
    ushort_t* Ps = ks ? P1 : P0;

    #pragma unroll
    for (int i = 0; i < 4; ++i) {
        int chunk = i * 1024 + tid;
        int row = chunk >> 6;
        int k8  = (chunk & 63) * 8;
        *(bf16x8*)&Qlds[row][k8] = *(const bf16x8*)&Q[(size_t)(q0 + row) * 512 + k8];
    }
    __syncthreads();

    f32x4 accO[4][2];
    #pragma unroll
    for (int r = 0; r < 4; ++r)
        #pragma unroll
        for (int c = 0; c < 2; ++c) accO[r][c] = (f32x4){0.f, 0.f, 0.f, 0.f};

    float lsum[4][4];
    #pragma unroll
    for (int r = 0; r < 4; ++r)
        #pragma unroll
        for (int g = 0; g < 4; ++g) lsum[r][g] = 0.f;

    const float sc = 0.04419417382415922f * 1.4426950408889634f;
    const int wd = wave * 32;

    for (int it = 0; it < 16; ++it) {
        const int j0  = kbase + it * 256;
        const int buf = it & 1;

        f32x4 accS[4];
        #pragma unroll
        for (int r = 0; r < 4; ++r) accS[r] = (f32x4){0.f, 0.f, 0.f, 0.f};
        const size_t keyrow = (size_t)(j0 + wave * 16 + col) * 512;
        #pragma unroll
        for (int h = 0; h < 2; ++h) {
            bf16x8 kb[8];
            #pragma unroll
            for (int kk = 0; kk < 8; ++kk)
                kb[kk] = *(const bf16x8*)&Q[keyrow + (h * 8 + kk) * 32 + quad * 8];
            #pragma unroll
            for (int kk = 0; kk < 8; ++kk) {
                const int cofs = (h * 8 + kk) * 32 + quad * 8;
                #pragma unroll
                for (int r = 0; r < 4; ++r) {
                    bf16x8 a = *(const bf16x8*)&Qlds[r * 16 + col][cofs];
                    accS[r] = mfma16(a, kb[kk], accS[r]);
                }
            }
        }

        bf16x8 vbA[8];
        #pragma unroll
        for (int kk = 0; kk < 4; ++kk)
            #pragma unroll
            for (int c = 0; c < 2; ++c)
                vbA[kk * 2 + c] = *(const bf16x8*)&embT[
                    (size_t)(wd + c * 16 + col) * NTOK + j0 + kk * 32 + quad * 8];

        #pragma unroll
        for (int r = 0; r < 4; ++r)
            #pragma unroll
            for (int g = 0; g < 4; ++g) {
                float p = exp2f(fminf(accS[r][g] * sc, 126.0f));
                lsum[r][g] += p;
                Plds[buf][r * 16 + quad * 4 + g][wave * 16 + col] = f2bf(p);
            }

        bf16x8 vbB[8];
        #pragma unroll
        for (int kk = 0; kk < 4; ++kk)
            #pragma unroll
            for (int c = 0; c < 2; ++c)
                vbB[kk * 2 + c] = *(const bf16x8*)&embT[
                    (size_t)(wd + c * 16 + col) * NTOK + j0 + (4 + kk) * 32 + quad * 8];

        __syncthreads();

        #pragma unroll
        for (int kk = 0; kk < 4; ++kk) {
            #pragma unroll
            for (int r = 0; r < 4; ++r) {
                bf16x8 a = *(const bf16x8*)&Plds[buf][r * 16 + col][kk * 32 + quad * 8];
                #pragma unroll
                for (int c = 0; c < 2; ++c)
                    accO[r][c] = mfma16(a, vbA[kk * 2 + c], accO[r][c]);
            }
        }
        #pragma unroll
        for (int kk = 0; kk < 4; ++kk) {
            #pragma unroll
            for (int r = 0; r < 4; ++r) {
                bf16x8 a = *(const bf16x8*)&Plds[buf][r * 16 + col][(4 + kk) * 32 + quad * 8];
                #pragma unroll
                for (int c = 0; c < 2; ++c)
                    accO[r][c] = mfma16(a, vbB[kk * 2 + c], accO[r][c]);
            }
        }
    }

    #pragma unroll
    for (int r = 0; r < 4; ++r)
        #pragma unroll
        for (int g = 0; g < 4; ++g) {
            float s = lsum[r][g];
            s += __shfl_xor(s, 1);
            s += __shfl_xor(s, 2);
            s += __shfl_xor(s, 4);
            s += __shfl_xor(s, 8);
            if (col == 0)
                Lp[wave][r * 16 + quad * 4 + g] = s;
        }
    __syncthreads();
    if (tid < 64) {
        float t = 0.f;
        #pragma unroll
        for (int w = 0; w < 16; ++w) t += Lp[w][tid];
        lsumA[(size_t)ks * NTOK + q0 + tid] = t;
    }

    #pragma unroll
    for (int r = 0; r < 4; ++r)
        #pragma unroll
        for (int c = 0; c < 2; ++c)
            #pragma unroll
            for (int g = 0; g < 4; ++g)
                Ps[(size_t)(q0 + r * 16 + quad * 4 + g) * DIM + wd + c * 16 + col]
                    = f2bf(accO[r][c][g]);
}

__global__ __launch_bounds__(512)
void finalize_kernel(const int* __restrict__ flag,
                     const ushort_t* __restrict__ P0, const ushort_t* __restrict__ P1,
                     const float* __restrict__ lsumA,
                     const ushort_t* __restrict__ Wb, const ushort_t* __restrict__ bb,
                     void* __restrict__ Out)
{
    __shared__ ushort_t Alds[64][LDA];
    const bool f32 = (*flag == 0);
    const int tid  = threadIdx.x;
    const int wave = tid >> 6;
    const int lane = tid & 63;
    const int quad = lane >> 4;
    const int col  = lane & 15;
    const int mblk = blockIdx.x * 64;

    #pragma unroll
    for (int i = 0; i < 8; ++i) {
        int chunk = i * 512 + tid;
        int row = chunk >> 6;
        int k8  = (chunk & 63) * 8;
        int m   = mblk + row;
        float rv = 1.0f / (lsumA[m] + lsumA[NTOK + m]);
        bf16x8 v0 = *(const bf16x8*)&P0[(size_t)m * 512 + k8];
        bf16x8 v1 = *(const bf16x8*)&P1[(size_t)m * 512 + k8];
        bf16x8 t;
        #pragma unroll
        for (int j = 0; j < 8; ++j) t[j] = f2bfh(((float)v0[j] + (float)v1[j]) * rv);
        *(bf16x8*)&Alds[row][k8] = t;
    }
    __syncthreads();

    f32x4 acc[4][4];
    #pragma unroll
    for (int r = 0; r < 4; ++r)
        #pragma unroll
        for (int c = 0; c < 4; ++c) acc[r][c] = (f32x4){0.f, 0.f, 0.f, 0.f};

    const int wcol = wave * 64;
    #pragma unroll
    for (int kk = 0; kk < 16; ++kk) {
        bf16x8 a[4];
        #pragma unroll
        for (int r = 0; r < 4; ++r)
            a[r] = *(const bf16x8*)&Alds[r * 16 + col][kk * 32 + quad * 8];
        #pragma unroll
        for (int c = 0; c < 4; ++c) {
            bf16x8 b = *(const bf16x8*)&Wb[(size_t)(wcol + c * 16 + col) * 512
                                           + kk * 32 + quad * 8];
            #pragma unroll
            for (int r = 0; r < 4; ++r)
                acc[r][c] = mfma16(a[r], b, acc[r][c]);
        }
    }

    #pragma unroll
    for (int r = 0; r < 4; ++r)
        #pragma unroll
        for (int c = 0; c < 4; ++c)
            #pragma unroll
            for (int g = 0; g < 4; ++g) {
                int m = mblk + r * 16 + quad * 4 + g;
                int n = wcol + c * 16 + col;
                float v = acc[r][c][g] + bf2f(bb[n]);
                if (f32) ((float*)Out)[(size_t)m * DIM + n] = v;
                else     ((ushort_t*)Out)[(size_t)m * DIM + n] = f2bf(v);
            }
}

// ---------------------------------------------------------------------------
// Fallback kernels (R13-proven) for smaller workspaces.
// ---------------------------------------------------------------------------
__global__ __launch_bounds__(256)
void transpose_kernel(const int* __restrict__ flag, const void* __restrict__ emb,
                      ushort_t* __restrict__ embT)
{
    __shared__ float tile[64][65];
    const bool f32 = (*flag == 0);
    const int t  = threadIdx.x;
    const int j0 = blockIdx.x * 64;
    const int d0 = blockIdx.y * 64;
    {
        int r = t >> 2, cs = (t & 3) * 16;
        if (f32) {
            const float* src = (const float*)emb + (size_t)(j0 + r) * DIM + d0 + cs;
            #pragma unroll
            for (int i = 0; i < 16; i += 4) {
                float4 v = *(const float4*)(src + i);
                tile[r][cs + i]     = v.x;
                tile[r][cs + i + 1] = v.y;
                tile[r][cs + i + 2] = v.z;
                tile[r][cs + i + 3] = v.w;
            }
        } else {
            const ushort_t* src = (const ushort_t*)emb + (size_t)(j0 + r) * DIM + d0 + cs;
            #pragma unroll
            for (int i = 0; i < 16; ++i) tile[r][cs + i] = bf2f(src[i]);
        }
    }
    __syncthreads();
    {
        int d = t >> 2, js = (t & 3) * 16;
        ushort_t buf[16];
        #pragma unroll
        for (int i = 0; i < 16; ++i) buf[i] = f2bf(tile[js + i][d]);
        ushort_t* dst = embT + (size_t)(d0 + d) * NTOK + j0 + js;
        *(uint4*)dst       = *(uint4*)&buf[0];
        *(uint4*)(dst + 8) = *(uint4*)&buf[8];
    }
}

__global__ __launch_bounds__(512)
void projq_kernel(const int* __restrict__ flag, const void* __restrict__ emb,
                  const void* __restrict__ W, const void* __restrict__ bias,
                  ushort_t* __restrict__ C)
{
    __shared__ ushort_t Alds[32][LDA];
    const bool f32 = (*flag == 0);
    const int tid  = threadIdx.x;
    const int wave = tid >> 6;
    const int lane = tid & 63;
    const int quad = lane >> 4;
    const int col  = lane & 15;
    const int mblk = blockIdx.x * 32;

    #pragma unroll
    for (int i = 0; i < 4; ++i) {
        int chunk = i * 512 + tid;
        int row = chunk >> 6;
        int k8  = (chunk & 63) * 8;
        *(bf16x8*)&Alds[row][k8] = load8(emb, (size_t)(mblk + row) * 512 + k8, f32);
    }
    __syncthreads();

    f32x4 acc[2][4];
    #pragma unroll
    for (int r = 0; r < 2; ++r)
        #pragma unroll
        for (int c = 0; c < 4; ++c) acc[r][c] = (f32x4){0.f, 0.f, 0.f, 0.f};

    const int wcol = wave * 64;
    #pragma unroll
    for (int kk = 0; kk < 16; ++kk) {
        bf16x8 a0 = *(const bf16x8*)&Alds[col][kk * 32 + quad * 8];
        bf16x8 a1 = *(const bf16x8*)&Alds[16 + col][kk * 32 + quad * 8];
        #pragma unroll
        for (int c = 0; c < 4; ++c) {
            bf16x8 b = load8(W, (size_t)(wcol + c * 16 + col) * 512 + kk * 32 + quad * 8, f32);
            acc[0][c] = mfma16(a0, b, acc[0][c]);
            acc[1][c] = mfma16(a1, b, acc[1][c]);
        }
    }

    #pragma unroll
    for (int r = 0; r < 2; ++r)
        #pragma unroll
        for (int c = 0; c < 4; ++c)
            #pragma unroll
            for (int g = 0; g < 4; ++g) {
                int m = mblk + r * 16 + quad * 4 + g;
                int n = wcol + c * 16 + col;
                C[(size_t)m * DIM + n] = f2bf(acc[r][c][g] + loadS(bias, n, f32));
            }
}

template <int VT>
__global__ __launch_bounds__(1024)
void attn_fused_kernel(const int* __restrict__ flag, const ushort_t* __restrict__ Q,
                       const void* __restrict__ embOrT, const void* __restrict__ Wv,
                       const void* __restrict__ bv, void* __restrict__ Out)
{
    __shared__ ushort_t Qlds[32][LDA];
    __shared__ ushort_t Plds[2][32][LDP];
    __shared__ float    Lpart[16][32];

    const bool f32 = (*flag == 0);
    const int tid  = threadIdx.x;
    const int wave = tid >> 6;
    const int lane = tid & 63;
    const int quad = lane >> 4;
    const int col  = lane & 15;
    const int q0   = blockIdx.x * 32;

    #pragma unroll
    for (int i = 0; i < 2; ++i) {
        int chunk = i * 1024 + tid;
        int row = chunk >> 6;
        int k8  = (chunk & 63) * 8;
        *(bf16x8*)&Qlds[row][k8] = *(const bf16x8*)&Q[(size_t)(q0 + row) * 512 + k8];
    }
    __syncthreads();

    f32x4 accO[2][2];
    #pragma unroll
    for (int r = 0; r < 2; ++r)
        #pragma unroll
        for (int c = 0; c < 2; ++c) accO[r][c] = (f32x4){0.f, 0.f, 0.f, 0.f};

    float lsum[2][4];
    #pragma unroll
    for (int r = 0; r < 2; ++r)
        #pragma unroll
        for (int g = 0; g < 4; ++g) lsum[r][g] = 0.f;

    const float sc = 0.04419417382415922f * 1.4426950408889634f;
    const int wOcol = wave * 32;

    for (int it = 0; it < 32; ++it) {
        const int j0  = it * 256;
        const int buf = it & 1;

        bf16x8 kb[16];
        const size_t keyrow = (size_t)(j0 + wave * 16 + col) * 512;
        #pragma unroll
        for (int kk = 0; kk < 16; ++kk)
            kb[kk] = *(const bf16x8*)&Q[keyrow + kk * 32 + quad * 8];

        f32x4 accS[2];
        accS[0] = (f32x4){0.f, 0.f, 0.f, 0.f};
        accS[1] = (f32x4){0.f, 0.f, 0.f, 0.f};
        #pragma unroll
        for (int kk = 0; kk < 16; ++kk) {
            bf16x8 a0 = *(const bf16x8*)&Qlds[col][kk * 32 + quad * 8];
            bf16x8 a1 = *(const bf16x8*)&Qlds[16 + col][kk * 32 + quad * 8];
            accS[0] = mfma16(a0, kb[kk], accS[0]);
            accS[1] = mfma16(a1, kb[kk], accS[1]);
        }

        bf16x8 vb[16];
        #pragma unroll
        for (int kk = 0; kk < 8; ++kk)
            #pragma unroll
            for (int c = 0; c < 2; ++c) {
                if (VT) {
                    vb[kk * 2 + c] = *(const bf16x8*)((const ushort_t*)embOrT
                        + (size_t)(wOcol + c * 16 + col) * NTOK + j0 + kk * 32 + quad * 8);
                } else {
                    size_t base = (size_t)(j0 + kk * 32 + quad * 8) * 512 + (wOcol + c * 16 + col);
                    bf16x8 b;
                    if (f32) {
                        const float* bp = (const float*)embOrT + base;
                        #pragma unroll
                        for (int j = 0; j < 8; ++j) b[j] = f2bfh(bp[(size_t)j * 512]);
                    } else {
                        const __bf16* bp = (const __bf16*)embOrT + base;
                        #pragma unroll
                        for (int j = 0; j < 8; ++j) b[j] = bp[(size_t)j * 512];
                    }
                    vb[kk * 2 + c] = b;
                }
            }

        #pragma unroll
        for (int r = 0; r < 2; ++r)
            #pragma unroll
            for (int g = 0; g < 4; ++g) {
                float p = exp2f(fminf(accS[r][g] * sc, 126.0f));
                lsum[r][g] += p;
                Plds[buf][r * 16 + quad * 4 + g][wave * 16 + col] = f2bf(p);
            }

        __syncthreads();

        #pragma unroll
        for (int kk = 0; kk < 8; ++kk) {
            bf16x8 a0 = *(const bf16x8*)&Plds[buf][col][kk * 32 + quad * 8];
            bf16x8 a1 = *(const bf16x8*)&Plds[buf][16 + col][kk * 32 + quad * 8];
            #pragma unroll
            for (int c = 0; c < 2; ++c) {
                accO[0][c] = mfma16(a0, vb[kk * 2 + c], accO[0][c]);
                accO[1][c] = mfma16(a1, vb[kk * 2 + c], accO[1][c]);
            }
        }
    }

    #pragma unroll
    for (int r = 0; r < 2; ++r)
        #pragma unroll
        for (int g = 0; g < 4; ++g) {
            float s = lsum[r][g];
            s += __shfl_xor(s, 1);
            s += __shfl_xor(s, 2);
            s += __shfl_xor(s, 4);
            s += __shfl_xor(s, 8);
            lsum[r][g] = s;
        }
    if (col == 0) {
        #pragma unroll
        for (int r = 0; r < 2; ++r)
            #pragma unroll
            for (int g = 0; g < 4; ++g)
                Lpart[wave][r * 16 + quad * 4 + g] = lsum[r][g];
    }
    __syncthreads();

    #pragma unroll
    for (int r = 0; r < 2; ++r) {
        float rinv[4];
        #pragma unroll
        for (int g = 0; g < 4; ++g) {
            float t = 0.f;
            #pragma unroll
            for (int w = 0; w < 16; ++w) t += Lpart[w][r * 16 + quad * 4 + g];
            rinv[g] = 1.0f / t;
        }
        #pragma unroll
        for (int c = 0; c < 2; ++c)
            #pragma unroll
            for (int g = 0; g < 4; ++g)
                Qlds[r * 16 + quad * 4 + g][wOcol + c * 16 + col] = f2bf(accO[r][c][g] * rinv[g]);
    }
    __syncthreads();

    f32x4 acc2[2][2];
    #pragma unroll
    for (int r = 0; r < 2; ++r)
        #pragma unroll
        for (int c = 0; c < 2; ++c) acc2[r][c] = (f32x4){0.f, 0.f, 0.f, 0.f};

    #pragma unroll
    for (int kk = 0; kk < 16; ++kk) {
        bf16x8 a0 = *(const bf16x8*)&Qlds[col][kk * 32 + quad * 8];
        bf16x8 a1 = *(const bf16x8*)&Qlds[16 + col][kk * 32 + quad * 8];
        #pragma unroll
        for (int c = 0; c < 2; ++c) {
            bf16x8 b = load8(Wv, (size_t)(wOcol + c * 16 + col) * 512 + kk * 32 + quad * 8, f32);
            acc2[0][c] = mfma16(a0, b, acc2[0][c]);
            acc2[1][c] = mfma16(a1, b, acc2[1][c]);
        }
    }

    #pragma unroll
    for (int r = 0; r < 2; ++r)
        #pragma unroll
        for (int c = 0; c < 2; ++c)
            #pragma unroll
            for (int g = 0; g < 4; ++g) {
                int m = q0 + r * 16 + quad * 4 + g;
                int n = wOcol + c * 16 + col;
                float v = acc2[r][c][g] + loadS(bv, n, f32);
                if (f32) ((float*)Out)[(size_t)m * DIM + n] = v;
                else     ((ushort_t*)Out)[(size_t)m * DIM + n] = f2bf(v);
            }
}

extern "C" void kernel_launch(void* const* d_in, const int* in_sizes, int n_in,
                              void* d_out, int out_size, void* d_ws, size_t ws_size,
                              hipStream_t stream)
{
    const void* emb = d_in[0];
    const void* Wqk = d_in[1];
    const void* bqk = d_in[2];
    const void* Wv  = d_in[3];
    const void* bv  = d_in[4];

    char* W = (char*)d_ws;
    int* flag = (int*)W;

    // R17 layout: flag | lsum4 (128KB) | Wqkb | Wvb | bqkb | bvb | embT | Qws | P[4]
    const size_t needC = 64 + 4 * (size_t)NTOK * 4 + 2 * (size_t)DIM * DIM * 2
                       + 2 * DIM * 2 + 6 * (size_t)NTOK * DIM * 2;   // ~49.1 MB
    // Old (R14) layout
    const size_t needA = 64 + 65536 + 2 * (size_t)DIM * DIM * 2 + 2 * DIM * 2
                       + 4 * (size_t)NTOK * DIM * 2;                  // ~33.1 MB
    const size_t needB = 64 + 2 * (size_t)NTOK * DIM * 2;             // 16.03 MB

    detect_kernel<<<dim3(1), dim3(64), 0, stream>>>((const ushort_t*)emb, flag);

    if (ws_size >= needC) {
        float*    lsum4 = (float*)(W + 64);                          // 128 KB
        ushort_t* Wqkb  = (ushort_t*)(W + 64 + 4 * (size_t)NTOK * 4);
        ushort_t* Wvb   = Wqkb + (size_t)DIM * DIM;
        ushort_t* bqkb  = Wvb + (size_t)DIM * DIM;
        ushort_t* bvb   = bqkb + DIM;
        ushort_t* embT  = bvb + DIM;                                 // 8 MB
        ushort_t* Qws   = embT + (size_t)DIM * NTOK;                 // 8 MB
        ushort_t* P4    = Qws + (size_t)DIM * NTOK;                  // 4 x 8 MB

        prep_kernel<<<dim3(128), dim3(256), 0, stream>>>(flag, Wqk, bqk, Wv, bv,
                                                         Wqkb, bqkb, Wvb, bvb);
        projqT_kernel<<<dim3(NTOK / 64), dim3(512), 0, stream>>>(flag, emb, Wqkb, bqkb,
                                                                 Qws, embT);
        attn128_kernel<<<dim3(256), dim3(512), 0, stream>>>(Qws, embT, P4, lsum4);
        finalize4_kernel<<<dim3(NTOK / 64), dim3(512), 0, stream>>>(flag, P4, lsum4,
                                                                    Wvb, bvb, d_out);
    } else if (ws_size >= needA) {
        float*    lsumA = (float*)(W + 64);                          // 64 KB
        ushort_t* Wqkb  = (ushort_t*)(W + 64 + 65536);
        ushort_t* Wvb   = Wqkb + (size_t)DIM * DIM;
        ushort_t* bqkb  = Wvb + (size_t)DIM * DIM;
        ushort_t* bvb   = bqkb + DIM;
        ushort_t* embT  = bvb + DIM;
        ushort_t* Qws   = embT + (size_t)DIM * NTOK;
        ushort_t* P0    = Qws + (size_t)DIM * NTOK;
        ushort_t* P1    = P0 + (size_t)NTOK * DIM;

        prep_kernel<<<dim3(128), dim3(256), 0, stream>>>(flag, Wqk, bqk, Wv, bv,
                                                         Wqkb, bqkb, Wvb, bvb);
        projqT_kernel<<<dim3(NTOK / 64), dim3(512), 0, stream>>>(flag, emb, Wqkb, bqkb,
                                                                 Qws, embT);
        attn64_kernel<<<dim3(256), dim3(1024), 0, stream>>>(Qws, embT, P0, P1, lsumA);
        finalize_kernel<<<dim3(NTOK / 64), dim3(512), 0, stream>>>(flag, P0, P1, lsumA,
                                                                   Wvb, bvb, d_out);
    } else if (ws_size >= needB) {
        ushort_t* embT2 = (ushort_t*)(W + 64);
        ushort_t* Qws2  = embT2 + (size_t)DIM * NTOK;
        transpose_kernel<<<dim3(128, 8), dim3(256), 0, stream>>>(flag, emb, embT2);
        projq_kernel<<<dim3(NTOK / 32), dim3(512), 0, stream>>>(flag, emb, Wqk, bqk, Qws2);
        attn_fused_kernel<1><<<dim3(NTOK / 32), dim3(1024), 0, stream>>>(
            flag, Qws2, embT2, Wv, bv, d_out);
    } else {
        ushort_t* Qsm = (ushort_t*)(W + 64);
        projq_kernel<<<dim3(NTOK / 32), dim3(512), 0, stream>>>(flag, emb, Wqk, bqk, Qsm);
        attn_fused_kernel<0><<<dim3(NTOK / 32), dim3(1024), 0, stream>>>(
            flag, Qsm, emb, Wv, bv, d_out);
    }
}

// Round 4
// 312.523 us; speedup vs baseline: 2.0533x; 1.0128x over previous
//
#include <hip/hip_runtime.h>
#include <hip/hip_bf16.h>

// N=8192, D=512.  Q = emb@Wqk^T+bqk (K==Q); out = softmax(QK^T/sqrt(512)) @ V.
// Softmax rows sum to 1 => out = (softmax(S)@emb) @ Wv^T + bv (V never built).
// R18: R17's attn128 (212us) decomposition: MFMA floor 66us, LDS-read floor
// ~100us (640 b128/iter at 1 read/MFMA — structural for 16x16x32 with one
// operand in regs; all alternatives break the 256-reg budget). Remaining
// levers: (1) XCD-aligned (qt,ks) remap so each XCD's L2 holds one
// key-quarter (2MB K + 2MB embT = its 4MB L2) instead of thrashing all 4
// quarters through L3; (2) satellites were 104us with only 128 blocks (half
// the CUs idle) — now 32-row tiles x 256 blocks. attn loop body unchanged
// (R17-proven, spill-free). Fallbacks unchanged.

#define NTOK 8192
#define DIM  512

typedef unsigned short ushort_t;
typedef unsigned int u32;
typedef __attribute__((ext_vector_type(8))) __bf16 bf16x8;
typedef __attribute__((ext_vector_type(4))) float f32x4;

__device__ __forceinline__ float bf2f(ushort_t u) {
    union { unsigned int i; float f; } v; v.i = ((unsigned int)u) << 16; return v.f;
}
__device__ __forceinline__ ushort_t f2bf(float f) {
    union { float f; unsigned int i; } v; v.f = f;
    unsigned int b = v.i;
    return (ushort_t)((b + 0x7FFFu + ((b >> 16) & 1u)) >> 16);   // RNE
}
__device__ __forceinline__ __bf16 f2bfh(float f) {
    union { ushort_t u; __bf16 h; } c; c.u = f2bf(f); return c.h;
}
__device__ __forceinline__ f32x4 mfma16(bf16x8 a, bf16x8 b, f32x4 c) {
    return __builtin_amdgcn_mfma_f32_16x16x32_bf16(a, b, c, 0, 0, 0);
}
__device__ __forceinline__ bf16x8 load8(const void* p, size_t idx, bool f32) {
    if (f32) {
        const float* f = (const float*)p + idx;
        bf16x8 r;
        #pragma unroll
        for (int j = 0; j < 8; ++j) r[j] = f2bfh(f[j]);
        return r;
    }
    return *(const bf16x8*)((const ushort_t*)p + idx);
}
__device__ __forceinline__ float loadS(const void* p, size_t idx, bool f32) {
    return f32 ? ((const float*)p)[idx] : bf2f(((const ushort_t*)p)[idx]);
}
__device__ __forceinline__ void gload_lds16(const ushort_t* g, ushort_t* l) {
    __builtin_amdgcn_global_load_lds(
        (const __attribute__((address_space(1))) u32*)g,
        (__attribute__((address_space(3))) u32*)l, 16, 0, 0);
}

#define LDA 520   // 260 dw, %32=4: uniform bank spread for b128 row reads
#define LDP 264

// ---------------------------------------------------------------------------
// Dtype probe: flag=1 => bf16 data, flag=0 => fp32.
// ---------------------------------------------------------------------------
__global__ void detect_kernel(const ushort_t* __restrict__ emb, int* __restrict__ flag)
{
    int lane = threadIdx.x;
    int cnt = 0;
    #pragma unroll
    for (int i = 0; i < 8; ++i) {
        ushort_t u = emb[(size_t)(lane * 8 + i) * 2];
        int a = u & 0x7FFF;
        int e = (u >> 7) & 0xFF;
        if (a == 0 || (e >= 111 && e <= 143)) cnt++;
    }
    cnt += __shfl_xor(cnt, 1);  cnt += __shfl_xor(cnt, 2);  cnt += __shfl_xor(cnt, 4);
    cnt += __shfl_xor(cnt, 8);  cnt += __shfl_xor(cnt, 16); cnt += __shfl_xor(cnt, 32);
    if (lane == 0) *flag = (cnt >= 460) ? 1 : 0;
}

// ---------------------------------------------------------------------------
// Prep: convert Wqk, Wv (512x512) + bqk, bv (512) to bf16 in ws.
// ---------------------------------------------------------------------------
__global__ __launch_bounds__(256)
void prep_kernel(const int* __restrict__ flag,
                 const void* __restrict__ Wqk, const void* __restrict__ bqk,
                 const void* __restrict__ Wv,  const void* __restrict__ bv,
                 ushort_t* __restrict__ Wqkb, ushort_t* __restrict__ bqkb,
                 ushort_t* __restrict__ Wvb,  ushort_t* __restrict__ bvb)
{
    const bool f32 = (*flag == 0);
    size_t gid = (size_t)blockIdx.x * 256 + threadIdx.x;   // 32768 threads
    size_t base = gid * 8;                                  // 262144 = 512*512
    *(bf16x8*)&Wqkb[base] = load8(Wqk, base, f32);
    *(bf16x8*)&Wvb[base]  = load8(Wv,  base, f32);
    if (gid < 64) {
        *(bf16x8*)&bqkb[base] = load8(bqk, base, f32);
        *(bf16x8*)&bvb[base]  = load8(bv,  base, f32);
    }
}

// ---------------------------------------------------------------------------
// Fused (R18: 32-row tiles, 256 blocks): Q[32 rows] = emb@Wqk^T+bqk AND embT
// columns, from one staged tile. 512 thr (8 waves); wave w owns cols [64w,+64).
// ---------------------------------------------------------------------------
__global__ __launch_bounds__(512)
void projqT_kernel(const int* __restrict__ flag, const void* __restrict__ emb,
                   const ushort_t* __restrict__ Wb, const ushort_t* __restrict__ bb,
                   ushort_t* __restrict__ C, ushort_t* __restrict__ embT)
{
    __shared__ ushort_t Alds[32][LDA];   // 33,280 B
    const bool f32 = (*flag == 0);
    const int tid  = threadIdx.x;
    const int wave = tid >> 6;
    const int lane = tid & 63;
    const int quad = lane >> 4;
    const int col  = lane & 15;
    const int mblk = blockIdx.x * 32;

    #pragma unroll
    for (int i = 0; i < 4; ++i) {
        int chunk = i * 512 + tid;
        int row = chunk >> 6;
        int k8  = (chunk & 63) * 8;
        *(bf16x8*)&Alds[row][k8] = load8(emb, (size_t)(mblk + row) * 512 + k8, f32);
    }
    __syncthreads();

    // ---- transpose store: thread t owns dim t, 32 tokens (64 B) ----
    {
        ushort_t buf[32];
        #pragma unroll
        for (int r = 0; r < 32; ++r) buf[r] = Alds[r][tid];
        ushort_t* dst = embT + (size_t)tid * NTOK + mblk;
        #pragma unroll
        for (int i = 0; i < 4; ++i)
            *(uint4*)(dst + i * 8) = *(uint4*)&buf[i * 8];
    }

    // ---- Q projection (32 rows x this wave's 64 cols) ----
    f32x4 acc[2][4];
    #pragma unroll
    for (int r = 0; r < 2; ++r)
        #pragma unroll
        for (int c = 0; c < 4; ++c) acc[r][c] = (f32x4){0.f, 0.f, 0.f, 0.f};

    const int wcol = wave * 64;
    #pragma unroll
    for (int kk = 0; kk < 16; ++kk) {
        bf16x8 a0 = *(const bf16x8*)&Alds[col][kk * 32 + quad * 8];
        bf16x8 a1 = *(const bf16x8*)&Alds[16 + col][kk * 32 + quad * 8];
        #pragma unroll
        for (int c = 0; c < 4; ++c) {
            bf16x8 b = *(const bf16x8*)&Wb[(size_t)(wcol + c * 16 + col) * 512
                                           + kk * 32 + quad * 8];
            acc[0][c] = mfma16(a0, b, acc[0][c]);
            acc[1][c] = mfma16(a1, b, acc[1][c]);
        }
    }

    #pragma unroll
    for (int r = 0; r < 2; ++r)
        #pragma unroll
        for (int c = 0; c < 4; ++c)
            #pragma unroll
            for (int g = 0; g < 4; ++g) {
                int m = mblk + r * 16 + quad * 4 + g;
                int n = wcol + c * 16 + col;
                C[(size_t)m * DIM + n] = f2bf(acc[r][c][g] + bf2f(bb[n]));
            }
}

// ---------------------------------------------------------------------------
// attn128 v3 (R17-proven core + R18 XCD-aligned remap): 256 blocks =
// 64 q-tiles (Tq=128) x 4 key-quarters, 512 thr = 8 waves, 2 waves/SIMD.
// Remap: ks=(bid&7)>>1, qt=((bid>>3)<<1)|(bid&1) so XCD pair {2k,2k+1}
// serves only quarter k (2MB K + 2MB embT fits the 4MB per-XCD L2).
// Wave w: S owns rows [q0+16w,+16) (Q in 64 VGPRs) x all 64 keys/iter;
// PV owns dims [64w,+64), accO[8][4] (128 AGPR). K: LDS dbuf via
// global_load_lds, pre-swizzled source (byte ^= (row&7)<<4), counted
// vmcnt(8). P: 16KB LDS, same XOR swizzle. 2 barriers/iter.
// ---------------------------------------------------------------------------
#define QT2  128
#define KT2  64
#define NIT2 32

__global__ __launch_bounds__(512, 2)
void attn128_kernel(const ushort_t* __restrict__ Q, const ushort_t* __restrict__ embT,
                    ushort_t* __restrict__ P, float* __restrict__ lsumA)
{
    __shared__ ushort_t Klds[2][KT2 * DIM];   // 131,072 B
    __shared__ ushort_t Plds[QT2 * KT2];      //  16,384 B (147,456 total)

    const int tid  = threadIdx.x;
    const int wave = tid >> 6;
    const int lane = tid & 63;
    const int quad = lane >> 4;
    const int col  = lane & 15;
    const int bid  = blockIdx.x;
    const int ks   = (bid & 7) >> 1;                      // XCD pair -> quarter
    const int qt   = ((bid >> 3) << 1) | (bid & 1);       // 0..63 bijective
    const int q0   = qt * QT2;
    const int kbase = ks * (NTOK / 4);
    ushort_t* Ps = P + (size_t)ks * NTOK * DIM;

    // Swizzle constants (K reads row=kt*16+col; P reads row=rt*16+col).
    const int s3 = col & 7;
    const int qo = (quad ^ (s3 & 3)) << 4;    // byte bits 4-5
    const int kx = (s3 >> 2) << 6;            // byte bit 6

    // ---- Q fragments: wave owns rows [q0+16w, +16), full K=512 (64 VGPR) ----
    bf16x8 qf[16];
    {
        const ushort_t* qrow = Q + (size_t)(q0 + wave * 16 + col) * DIM + quad * 8;
        #pragma unroll
        for (int kk = 0; kk < 16; ++kk)
            qf[kk] = *(const bf16x8*)(qrow + kk * 32);
    }

    // K-read byte bases per key-tile
    int rbk[4];
    #pragma unroll
    for (int kt = 0; kt < 4; ++kt)
        rbk[kt] = (((kt * 16 + col) << 10) | qo) ^ kx;

    const int pwrow = wave * 16 + quad * 4;          // P-write row base (+g)
    const int pb    = ((col << 7) | qo) ^ kx;        // PV-read byte base

    // ---- stage K(0) into buf 0 ----
    {
        const size_t gb = (size_t)kbase * DIM;
        #pragma unroll
        for (int i = 0; i < 8; ++i) {
            const int r = wave * 8 + i;
            gload_lds16(Q + gb + (size_t)r * DIM + ((lane ^ (r & 7)) << 3),
                        &Klds[0][r * DIM]);
        }
    }

    f32x4 accO[8][4];
    #pragma unroll
    for (int r = 0; r < 8; ++r)
        #pragma unroll
        for (int c = 0; c < 4; ++c) accO[r][c] = (f32x4){0.f, 0.f, 0.f, 0.f};
    float lsum[4] = {0.f, 0.f, 0.f, 0.f};

    const float sc = 0.04419417382415922f * 1.4426950408889634f;  // 1/sqrt(512)*log2e
    const int wd = wave * 64;

    for (int it = 0; it < NIT2; ++it) {
        const int cur = it & 1;
        const char* Kc = (const char*)&Klds[cur][0];
        const int j0 = kbase + it * KT2;

        // ---- prefetch K(t+1); counted vmcnt waits only for K(t)'s loads ----
        if (it + 1 < NIT2) {
            const size_t gb = (size_t)(j0 + KT2) * DIM;
            ushort_t* dst = &Klds[cur ^ 1][0];
            #pragma unroll
            for (int i = 0; i < 8; ++i) {
                const int r = wave * 8 + i;
                gload_lds16(Q + gb + (size_t)r * DIM + ((lane ^ (r & 7)) << 3),
                            dst + r * DIM);
            }
            asm volatile("s_waitcnt vmcnt(8)" ::: "memory");
        } else {
            asm volatile("s_waitcnt vmcnt(0)" ::: "memory");
        }
        // Top barrier: K(t) staged AND all waves done with P(t-1)
        __builtin_amdgcn_s_barrier();

        // ---- S = Q(wave's 16 rows) @ K(all 64 keys)^T, A from registers ----
        f32x4 accS[4];
        #pragma unroll
        for (int kt = 0; kt < 4; ++kt) accS[kt] = (f32x4){0.f, 0.f, 0.f, 0.f};
        __builtin_amdgcn_s_setprio(1);
        #pragma unroll
        for (int kk = 0; kk < 16; ++kk)
            #pragma unroll
            for (int kt = 0; kt < 4; ++kt) {
                bf16x8 kb = *(const bf16x8*)(Kc + (rbk[kt] ^ (kk << 6)));
                accS[kt] = mfma16(qf[kk], kb, accS[kt]);
            }
        __builtin_amdgcn_s_setprio(0);

        // ---- P = exp2(S*sc) -> swizzled Plds; row sums (rows wave-owned) ----
        #pragma unroll
        for (int kt = 0; kt < 4; ++kt)
            #pragma unroll
            for (int g = 0; g < 4; ++g) {
                float p = exp2f(fminf(accS[kt][g] * sc, 126.0f));
                lsum[g] += p;
                const int prow = pwrow + g;
                Plds[(prow << 6) | ((kt * 16 + col) ^ ((prow & 7) << 3))] = f2bf(p);
            }

        // ---- vb kslot 0 (global; latency hidden under exp + barrier) ----
        const ushort_t* eb = embT + (size_t)(wd + col) * NTOK + j0 + quad * 8;
        bf16x8 vb0[4];
        #pragma unroll
        for (int dt = 0; dt < 4; ++dt)
            vb0[dt] = *(const bf16x8*)(eb + (size_t)(dt * 16) * NTOK);

        // ---- B1: P visible (LDS only; K-prefetch stays in flight) ----
        asm volatile("s_waitcnt lgkmcnt(0)" ::: "memory");
        __builtin_amdgcn_s_barrier();

        // ---- PV kslot 0: O += P[:, 0:32] @ embT[:, 0:32]^T ----
        __builtin_amdgcn_s_setprio(1);
        #pragma unroll
        for (int rt = 0; rt < 8; ++rt) {
            bf16x8 pa = *(const bf16x8*)((const char*)Plds + (rt * 2048 + pb));
            #pragma unroll
            for (int dt = 0; dt < 4; ++dt)
                accO[rt][dt] = mfma16(pa, vb0[dt], accO[rt][dt]);
        }
        __builtin_amdgcn_s_setprio(0);

        // ---- vb kslot 1 + PV kslot 1 ----
        bf16x8 vb1[4];
        #pragma unroll
        for (int dt = 0; dt < 4; ++dt)
            vb1[dt] = *(const bf16x8*)(eb + (size_t)(dt * 16) * NTOK + 32);

        __builtin_amdgcn_s_setprio(1);
        #pragma unroll
        for (int rt = 0; rt < 8; ++rt) {
            bf16x8 pa = *(const bf16x8*)((const char*)Plds + (rt * 2048 + (pb ^ 64)));
            #pragma unroll
            for (int dt = 0; dt < 4; ++dt)
                accO[rt][dt] = mfma16(pa, vb1[dt], accO[rt][dt]);
        }
        __builtin_amdgcn_s_setprio(0);
        // No end barrier: next iter's top barrier fences P(t) vs P(t+1).
    }

    // ---- row sums: reduce over col lanes (keys); rows wave-owned ----
    #pragma unroll
    for (int g = 0; g < 4; ++g) {
        float s = lsum[g];
        s += __shfl_xor(s, 1);
        s += __shfl_xor(s, 2);
        s += __shfl_xor(s, 4);
        s += __shfl_xor(s, 8);
        if (col == 0)
            lsumA[(size_t)ks * NTOK + q0 + pwrow + g] = s;
    }

    // ---- store O partial (pre-normalization) ----
    #pragma unroll
    for (int rt = 0; rt < 8; ++rt)
        #pragma unroll
        for (int dt = 0; dt < 4; ++dt)
            #pragma unroll
            for (int g = 0; g < 4; ++g)
                Ps[(size_t)(q0 + rt * 16 + quad * 4 + g) * DIM + wd + dt * 16 + col]
                    = f2bf(accO[rt][dt][g]);
}

// ---------------------------------------------------------------------------
// Finalize4 (R18: 32-row tiles, 256 blocks): T = (P0..P3)/(l0..l3),
// out = T @ Wv^T + bv.
// ---------------------------------------------------------------------------
__global__ __launch_bounds__(512)
void finalize4_kernel(const int* __restrict__ flag,
                      const ushort_t* __restrict__ P, const float* __restrict__ lsumA,
                      const ushort_t* __restrict__ Wb, const ushort_t* __restrict__ bb,
                      void* __restrict__ Out)
{
    __shared__ ushort_t Alds[32][LDA];
    const bool f32 = (*flag == 0);
    const int tid  = threadIdx.x;
    const int wave = tid >> 6;
    const int lane = tid & 63;
    const int quad = lane >> 4;
    const int col  = lane & 15;
    const int mblk = blockIdx.x * 32;
    const size_t PSZ = (size_t)NTOK * DIM;

    #pragma unroll
    for (int i = 0; i < 4; ++i) {
        int chunk = i * 512 + tid;
        int row = chunk >> 6;
        int k8  = (chunk & 63) * 8;
        int m   = mblk + row;
        float rv = 1.0f / (lsumA[m] + lsumA[NTOK + m]
                         + lsumA[2 * NTOK + m] + lsumA[3 * NTOK + m]);
        size_t off = (size_t)m * 512 + k8;
        bf16x8 v0 = *(const bf16x8*)&P[off];
        bf16x8 v1 = *(const bf16x8*)&P[PSZ + off];
        bf16x8 v2 = *(const bf16x8*)&P[2 * PSZ + off];
        bf16x8 v3 = *(const bf16x8*)&P[3 * PSZ + off];
        bf16x8 t;
        #pragma unroll
        for (int j = 0; j < 8; ++j)
            t[j] = f2bfh(((float)v0[j] + (float)v1[j] + (float)v2[j] + (float)v3[j]) * rv);
        *(bf16x8*)&Alds[row][k8] = t;
    }
    __syncthreads();

    f32x4 acc[2][4];
    #pragma unroll
    for (int r = 0; r < 2; ++r)
        #pragma unroll
        for (int c = 0; c < 4; ++c) acc[r][c] = (f32x4){0.f, 0.f, 0.f, 0.f};

    const int wcol = wave * 64;
    #pragma unroll
    for (int kk = 0; kk < 16; ++kk) {
        bf16x8 a0 = *(const bf16x8*)&Alds[col][kk * 32 + quad * 8];
        bf16x8 a1 = *(const bf16x8*)&Alds[16 + col][kk * 32 + quad * 8];
        #pragma unroll
        for (int c = 0; c < 4; ++c) {
            bf16x8 b = *(const bf16x8*)&Wb[(size_t)(wcol + c * 16 + col) * 512
                                           + kk * 32 + quad * 8];
            acc[0][c] = mfma16(a0, b, acc[0][c]);
            acc[1][c] = mfma16(a1, b, acc[1][c]);
        }
    }

    #pragma unroll
    for (int r = 0; r < 2; ++r)
        #pragma unroll
        for (int c = 0; c < 4; ++c)
            #pragma unroll
            for (int g = 0; g < 4; ++g) {
                int m = mblk + r * 16 + quad * 4 + g;
                int n = wcol + c * 16 + col;
                float v = acc[r][c][g] + bf2f(bb[n]);
                if (f32) ((float*)Out)[(size_t)m * DIM + n] = v;
                else     ((ushort_t*)Out)[(size_t)m * DIM + n] = f2bf(v);
            }
}

// ---------------------------------------------------------------------------
// R13-proven attn64 + finalize (fallback for mid-size workspace).
// ---------------------------------------------------------------------------
__global__ __launch_bounds__(1024)
void attn64_kernel(const ushort_t* __restrict__ Q, const ushort_t* __restrict__ embT,
                   ushort_t* __restrict__ P0, ushort_t* __restrict__ P1,
                   float* __restrict__ lsumA)
{
    __shared__ ushort_t Qlds[64][LDA];
    __shared__ ushort_t Plds[2][64][LDP];
    __shared__ float    Lp[16][64];

    const int tid  = threadIdx.x;
    const int wave = tid >> 6;
    const int lane = tid & 63;
    const int quad = lane >> 4;
    const int col  = lane & 15;
    const int qt   = blockIdx.x & 127;
    const int ks   = blockIdx.x >> 7;
    const int q0   = qt * 64;
    const int kbase = ks * 4096;
    ushort_t* Ps = ks ? P1 : P0;

    #pragma unroll
    for (int i = 0; i < 4; ++i) {
        int chunk = i * 1024 + tid;
        int row = chunk >> 6;
        int k8  = (chunk & 63) * 8;
        *(bf16x8*)&Qlds[row][k8] = *(const bf16x8*)&Q[(size_t)(q0 + row) * 512 + k8];
    }
    __syncthreads();

    f32x4 accO[4][2];
    #pragma unroll
    for (int r = 0; r < 4; ++r)
        #pragma unroll
        for (int c = 0; c < 2; ++c) accO[r][c] = (f32x4){0.f, 0.f, 0.f, 0.f};

    float lsum[4][4];
    #pragma unroll
    for (int r = 0; r < 4; ++r)
        #pragma unroll
        for (int g = 0; g < 4; ++g) lsum[r][g] = 0.f;

    const float sc = 0.04419417382415922f * 1.4426950408889634f;
    const int wd = wave * 32;

    for (int it = 0; it < 16; ++it) {
        const int j0  = kbase + it * 256;
        const int buf = it & 1;

        f32x4 accS[4];
        #pragma unroll
        for (int r = 0; r < 4; ++r) accS[r] = (f32x4){0.f, 0.f, 0.f, 0.f};
        const size_t keyrow = (size_t)(j0 + wave * 16 + col) * 512;
        #pragma unroll
        for (int h = 0; h < 2; ++h) {
            bf16x8 kb[8];
            #pragma unroll
            for (int kk = 0; kk < 8; ++kk)
                kb[kk] = *(const bf16x8*)&Q[keyrow + (h * 8 + kk) * 32 + quad * 8];
            #pragma unroll
            for (int kk = 0; kk < 8; ++kk) {
                const int cofs = (h * 8 + kk) * 32 + quad * 8;
                #pragma unroll
                for (int r = 0; r < 4; ++r) {
                    bf16x8 a = *(const bf16x8*)&Qlds[r * 16 + col][cofs];
                    accS[r] = mfma16(a, kb[kk], accS[r]);
                }
            }
        }

        bf16x8 vbA[8];
        #pragma unroll
        for (int kk = 0; kk < 4; ++kk)
            #pragma unroll
            for (int c = 0; c < 2; ++c)
                vbA[kk * 2 + c] = *(const bf16x8*)&embT[
                    (size_t)(wd + c * 16 + col) * NTOK + j0 + kk * 32 + quad * 8];

        #pragma unroll
        for (int r = 0; r < 4; ++r)
            #pragma unroll
            for (int g = 0; g < 4; ++g) {
                float p = exp2f(fminf(accS[r][g] * sc, 126.0f));
                lsum[r][g] += p;
                Plds[buf][r * 16 + quad * 4 + g][wave * 16 + col] = f2bf(p);
            }

        bf16x8 vbB[8];
        #pragma unroll
        for (int kk = 0; kk < 4; ++kk)
            #pragma unroll
            for (int c = 0; c < 2; ++c)
                vbB[kk * 2 + c] = *(const bf16x8*)&embT[
                    (size_t)(wd + c * 16 + col) * NTOK + j0 + (4 + kk) * 32 + quad * 8];

        __syncthreads();

        #pragma unroll
        for (int kk = 0; kk < 4; ++kk) {
            #pragma unroll
            for (int r = 0; r < 4; ++r) {
                bf16x8 a = *(const bf16x8*)&Plds[buf][r * 16 + col][kk * 32 + quad * 8];
                #pragma unroll
                for (int c = 0; c < 2; ++c)
                    accO[r][c] = mfma16(a, vbA[kk * 2 + c], accO[r][c]);
            }
        }
        #pragma unroll
        for (int kk = 0; kk < 4; ++kk) {
            #pragma unroll
            for (int r = 0; r < 4; ++r) {
                bf16x8 a = *(const bf16x8*)&Plds[buf][r * 16 + col][(4 + kk) * 32 + quad * 8];
                #pragma unroll
                for (int c = 0; c < 2; ++c)
                    accO[r][c] = mfma16(a, vbB[kk * 2 + c], accO[r][c]);
            }
        }
    }

    #pragma unroll
    for (int r = 0; r < 4; ++r)
        #pragma unroll
        for (int g = 0; g < 4; ++g) {
            float s = lsum[r][g];
            s += __shfl_xor(s, 1);
            s += __shfl_xor(s, 2);
            s += __shfl_xor(s, 4);
            s += __shfl_xor(s, 8);
            if (col == 0)
                Lp[wave][r * 16 + quad * 4 + g] = s;
        }
    __syncthreads();
    if (tid < 64) {
        float t = 0.f;
        #pragma unroll
        for (int w = 0; w < 16; ++w) t += Lp[w][tid];
        lsumA[(size_t)ks * NTOK + q0 + tid] = t;
    }

    #pragma unroll
    for (int r = 0; r < 4; ++r)
        #pragma unroll
        for (int c = 0; c < 2; ++c)
            #pragma unroll
            for (int g = 0; g < 4; ++g)
                Ps[(size_t)(q0 + r * 16 + quad * 4 + g) * DIM + wd + c * 16 + col]
                    = f2bf(accO[r][c][g]);
}

__global__ __launch_bounds__(512)
void finalize_kernel(const int* __restrict__ flag,
                     const ushort_t* __restrict__ P0, const ushort_t* __restrict__ P1,
                     const float* __restrict__ lsumA,
                     const ushort_t* __restrict__ Wb, const ushort_t* __restrict__ bb,
                     void* __restrict__ Out)
{
    __shared__ ushort_t Alds[64][LDA];
    const bool f32 = (*flag == 0);
    const int tid  = threadIdx.x;
    const int wave = tid >> 6;
    const int lane = tid & 63;
    const int quad = lane >> 4;
    const int col  = lane & 15;
    const int mblk = blockIdx.x * 64;

    #pragma unroll
    for (int i = 0; i < 8; ++i) {
        int chunk = i * 512 + tid;
        int row = chunk >> 6;
        int k8  = (chunk & 63) * 8;
        int m   = mblk + row;
        float rv = 1.0f / (lsumA[m] + lsumA[NTOK + m]);
        bf16x8 v0 = *(const bf16x8*)&P0[(size_t)m * 512 + k8];
        bf16x8 v1 = *(const bf16x8*)&P1[(size_t)m * 512 + k8];
        bf16x8 t;
        #pragma unroll
        for (int j = 0; j < 8; ++j) t[j] = f2bfh(((float)v0[j] + (float)v1[j]) * rv);
        *(bf16x8*)&Alds[row][k8] = t;
    }
    __syncthreads();

    f32x4 acc[4][4];
    #pragma unroll
    for (int r = 0; r < 4; ++r)
        #pragma unroll
        for (int c = 0; c < 4; ++c) acc[r][c] = (f32x4){0.f, 0.f, 0.f, 0.f};

    const int wcol = wave * 64;
    #pragma unroll
    for (int kk = 0; kk < 16; ++kk) {
        bf16x8 a[4];
        #pragma unroll
        for (int r = 0; r < 4; ++r)
            a[r] = *(const bf16x8*)&Alds[r * 16 + col][kk * 32 + quad * 8];
        #pragma unroll
        for (int c = 0; c < 4; ++c) {
            bf16x8 b = *(const bf16x8*)&Wb[(size_t)(wcol + c * 16 + col) * 512
                                           + kk * 32 + quad * 8];
            #pragma unroll
            for (int r = 0; r < 4; ++r)
                acc[r][c] = mfma16(a[r], b, acc[r][c]);
        }
    }

    #pragma unroll
    for (int r = 0; r < 4; ++r)
        #pragma unroll
        for (int c = 0; c < 4; ++c)
            #pragma unroll
            for (int g = 0; g < 4; ++g) {
                int m = mblk + r * 16 + quad * 4 + g;
                int n = wcol + c * 16 + col;
                float v = acc[r][c][g] + bf2f(bb[n]);
                if (f32) ((float*)Out)[(size_t)m * DIM + n] = v;
                else     ((ushort_t*)Out)[(size_t)m * DIM + n] = f2bf(v);
            }
}

// ---------------------------------------------------------------------------
// Fallback kernels (R13-proven) for smaller workspaces.
// ---------------------------------------------------------------------------
__global__ __launch_bounds__(256)
void transpose_kernel(const int* __restrict__ flag, const void* __restrict__ emb,
                      ushort_t* __restrict__ embT)
{
    __shared__ float tile[64][65];
    const bool f32 = (*flag == 0);
    const int t  = threadIdx.x;
    const int j0 = blockIdx.x * 64;
    const int d0 = blockIdx.y * 64;
    {
        int r = t >> 2, cs = (t & 3) * 16;
        if (f32) {
            const float* src = (const float*)emb + (size_t)(j0 + r) * DIM + d0 + cs;
            #pragma unroll
            for (int i = 0; i < 16; i += 4) {
                float4 v = *(const float4*)(src + i);
                tile[r][cs + i]     = v.x;
                tile[r][cs + i + 1] = v.y;
                tile[r][cs + i + 2] = v.z;
                tile[r][cs + i + 3] = v.w;
            }
        } else {
            const ushort_t* src = (const ushort_t*)emb + (size_t)(j0 + r) * DIM + d0 + cs;
            #pragma unroll
            for (int i = 0; i < 16; ++i) tile[r][cs + i] = bf2f(src[i]);
        }
    }
    __syncthreads();
    {
        int d = t >> 2, js = (t & 3) * 16;
        ushort_t buf[16];
        #pragma unroll
        for (int i = 0; i < 16; ++i) buf[i] = f2bf(tile[js + i][d]);
        ushort_t* dst = embT + (size_t)(d0 + d) * NTOK + j0 + js;
        *(uint4*)dst       = *(uint4*)&buf[0];
        *(uint4*)(dst + 8) = *(uint4*)&buf[8];
    }
}

__global__ __launch_bounds__(512)
void projq_kernel(const int* __restrict__ flag, const void* __restrict__ emb,
                  const void* __restrict__ W, const void* __restrict__ bias,
                  ushort_t* __restrict__ C)
{
    __shared__ ushort_t Alds[32][LDA];
    const bool f32 = (*flag == 0);
    const int tid  = threadIdx.x;
    const int wave = tid >> 6;
    const int lane = tid & 63;
    const int quad = lane >> 4;
    const int col  = lane & 15;
    const int mblk = blockIdx.x * 32;

    #pragma unroll
    for (int i = 0; i < 4; ++i) {
        int chunk = i * 512 + tid;
        int row = chunk >> 6;
        int k8  = (chunk & 63) * 8;
        *(bf16x8*)&Alds[row][k8] = load8(emb, (size_t)(mblk + row) * 512 + k8, f32);
    }
    __syncthreads();

    f32x4 acc[2][4];
    #pragma unroll
    for (int r = 0; r < 2; ++r)
        #pragma unroll
        for (int c = 0; c < 4; ++c) acc[r][c] = (f32x4){0.f, 0.f, 0.f, 0.f};

    const int wcol = wave * 64;
    #pragma unroll
    for (int kk = 0; kk < 16; ++kk) {
        bf16x8 a0 = *(const bf16x8*)&Alds[col][kk * 32 + quad * 8];
        bf16x8 a1 = *(const bf16x8*)&Alds[16 + col][kk * 32 + quad * 8];
        #pragma unroll
        for (int c = 0; c < 4; ++c) {
            bf16x8 b = load8(W, (size_t)(wcol + c * 16 + col) * 512 + kk * 32 + quad * 8, f32);
            acc[0][c] = mfma16(a0, b, acc[0][c]);
            acc[1][c] = mfma16(a1, b, acc[1][c]);
        }
    }

    #pragma unroll
    for (int r = 0; r < 2; ++r)
        #pragma unroll
        for (int c = 0; c < 4; ++c)
            #pragma unroll
            for (int g = 0; g < 4; ++g) {
                int m = mblk + r * 16 + quad * 4 + g;
                int n = wcol + c * 16 + col;
                C[(size_t)m * DIM + n] = f2bf(acc[r][c][g] + loadS(bias, n, f32));
            }
}

template <int VT>
__global__ __launch_bounds__(1024)
void attn_fused_kernel(const int* __restrict__ flag, const ushort_t* __restrict__ Q,
                       const void* __restrict__ embOrT, const void* __restrict__ Wv,
                       const void* __restrict__ bv, void* __restrict__ Out)
{
    __shared__ ushort_t Qlds[32][LDA];
    __shared__ ushort_t Plds[2][32][LDP];
    __shared__ float    Lpart[16][32];

    const bool f32 = (*flag == 0);
    const int tid  = threadIdx.x;
    const int wave = tid >> 6;
    const int lane = tid & 63;
    const int quad = lane >> 4;
    const int col  = lane & 15;
    const int q0   = blockIdx.x * 32;

    #pragma unroll
    for (int i = 0; i < 2; ++i) {
        int chunk = i * 1024 + tid;
        int row = chunk >> 6;
        int k8  = (chunk & 63) * 8;
        *(bf16x8*)&Qlds[row][k8] = *(const bf16x8*)&Q[(size_t)(q0 + row) * 512 + k8];
    }
    __syncthreads();

    f32x4 accO[2][2];
    #pragma unroll
    for (int r = 0; r < 2; ++r)
        #pragma unroll
        for (int c = 0; c < 2; ++c) accO[r][c] = (f32x4){0.f, 0.f, 0.f, 0.f};

    float lsum[2][4];
    #pragma unroll
    for (int r = 0; r < 2; ++r)
        #pragma unroll
        for (int g = 0; g < 4; ++g) lsum[r][g] = 0.f;

    const float sc = 0.04419417382415922f * 1.4426950408889634f;
    const int wOcol = wave * 32;

    for (int it = 0; it < 32; ++it) {
        const int j0  = it * 256;
        const int buf = it & 1;

        bf16x8 kb[16];
        const size_t keyrow = (size_t)(j0 + wave * 16 + col) * 512;
        #pragma unroll
        for (int kk = 0; kk < 16; ++kk)
            kb[kk] = *(const bf16x8*)&Q[keyrow + kk * 32 + quad * 8];

        f32x4 accS[2];
        accS[0] = (f32x4){0.f, 0.f, 0.f, 0.f};
        accS[1] = (f32x4){0.f, 0.f, 0.f, 0.f};
        #pragma unroll
        for (int kk = 0; kk < 16; ++kk) {
            bf16x8 a0 = *(const bf16x8*)&Qlds[col][kk * 32 + quad * 8];
            bf16x8 a1 = *(const bf16x8*)&Qlds[16 + col][kk * 32 + quad * 8];
            accS[0] = mfma16(a0, kb[kk], accS[0]);
            accS[1] = mfma16(a1, kb[kk], accS[1]);
        }

        bf16x8 vb[16];
        #pragma unroll
        for (int kk = 0; kk < 8; ++kk)
            #pragma unroll
            for (int c = 0; c < 2; ++c) {
                if (VT) {
                    vb[kk * 2 + c] = *(const bf16x8*)((const ushort_t*)embOrT
                        + (size_t)(wOcol + c * 16 + col) * NTOK + j0 + kk * 32 + quad * 8);
                } else {
                    size_t base = (size_t)(j0 + kk * 32 + quad * 8) * 512 + (wOcol + c * 16 + col);
                    bf16x8 b;
                    if (f32) {
                        const float* bp = (const float*)embOrT + base;
                        #pragma unroll
                        for (int j = 0; j < 8; ++j) b[j] = f2bfh(bp[(size_t)j * 512]);
                    } else {
                        const __bf16* bp = (const __bf16*)embOrT + base;
                        #pragma unroll
                        for (int j = 0; j < 8; ++j) b[j] = bp[(size_t)j * 512];
                    }
                    vb[kk * 2 + c] = b;
                }
            }

        #pragma unroll
        for (int r = 0; r < 2; ++r)
            #pragma unroll
            for (int g = 0; g < 4; ++g) {
                float p = exp2f(fminf(accS[r][g] * sc, 126.0f));
                lsum[r][g] += p;
                Plds[buf][r * 16 + quad * 4 + g][wave * 16 + col] = f2bf(p);
            }

        __syncthreads();

        #pragma unroll
        for (int kk = 0; kk < 8; ++kk) {
            bf16x8 a0 = *(const bf16x8*)&Plds[buf][col][kk * 32 + quad * 8];
            bf16x8 a1 = *(const bf16x8*)&Plds[buf][16 + col][kk * 32 + quad * 8];
            #pragma unroll
            for (int c = 0; c < 2; ++c) {
                accO[0][c] = mfma16(a0, vb[kk * 2 + c], accO[0][c]);
                accO[1][c] = mfma16(a1, vb[kk * 2 + c], accO[1][c]);
            }
        }
    }

    #pragma unroll
    for (int r = 0; r < 2; ++r)
        #pragma unroll
        for (int g = 0; g < 4; ++g) {
            float s = lsum[r][g];
            s += __shfl_xor(s, 1);
            s += __shfl_xor(s, 2);
            s += __shfl_xor(s, 4);
            s += __shfl_xor(s, 8);
            lsum[r][g] = s;
        }
    if (col == 0) {
        #pragma unroll
        for (int r = 0; r < 2; ++r)
            #pragma unroll
            for (int g = 0; g < 4; ++g)
                Lpart[wave][r * 16 + quad * 4 + g] = lsum[r][g];
    }
    __syncthreads();

    #pragma unroll
    for (int r = 0; r < 2; ++r) {
        float rinv[4];
        #pragma unroll
        for (int g = 0; g < 4; ++g) {
            float t = 0.f;
            #pragma unroll
            for (int w = 0; w < 16; ++w) t += Lpart[w][r * 16 + quad * 4 + g];
            rinv[g] = 1.0f / t;
        }
        #pragma unroll
        for (int c = 0; c < 2; ++c)
            #pragma unroll
            for (int g = 0; g < 4; ++g)
                Qlds[r * 16 + quad * 4 + g][wOcol + c * 16 + col] = f2bf(accO[r][c][g] * rinv[g]);
    }
    __syncthreads();

    f32x4 acc2[2][2];
    #pragma unroll
    for (int r = 0; r < 2; ++r)
        #pragma unroll
        for (int c = 0; c < 2; ++c) acc2[r][c] = (f32x4){0.f, 0.f, 0.f, 0.f};

    #pragma unroll
    for (int kk = 0; kk < 16; ++kk) {
        bf16x8 a0 = *(const bf16x8*)&Qlds[col][kk * 32 + quad * 8];
        bf16x8 a1 = *(const bf16x8*)&Qlds[16 + col][kk * 32 + quad * 8];
        #pragma unroll
        for (int c = 0; c < 2; ++c) {
            bf16x8 b = load8(Wv, (size_t)(wOcol + c * 16 + col) * 512 + kk * 32 + quad * 8, f32);
            acc2[0][c] = mfma16(a0, b, acc2[0][c]);
            acc2[1][c] = mfma16(a1, b, acc2[1][c]);
        }
    }

    #pragma unroll
    for (int r = 0; r < 2; ++r)
        #pragma unroll
        for (int c = 0; c < 2; ++c)
            #pragma unroll
            for (int g = 0; g < 4; ++g) {
                int m = q0 + r * 16 + quad * 4 + g;
                int n = wOcol + c * 16 + col;
                float v = acc2[r][c][g] + loadS(bv, n, f32);
                if (f32) ((float*)Out)[(size_t)m * DIM + n] = v;
                else     ((ushort_t*)Out)[(size_t)m * DIM + n] = f2bf(v);
            }
}

extern "C" void kernel_launch(void* const* d_in, const int* in_sizes, int n_in,
                              void* d_out, int out_size, void* d_ws, size_t ws_size,
                              hipStream_t stream)
{
    const void* emb = d_in[0];
    const void* Wqk = d_in[1];
    const void* bqk = d_in[2];
    const void* Wv  = d_in[3];
    const void* bv  = d_in[4];

    char* W = (char*)d_ws;
    int* flag = (int*)W;

    // R18 layout: flag | lsum4 (128KB) | Wqkb | Wvb | bqkb | bvb | embT | Qws | P[4]
    const size_t needC = 64 + 4 * (size_t)NTOK * 4 + 2 * (size_t)DIM * DIM * 2
                       + 2 * DIM * 2 + 6 * (size_t)NTOK * DIM * 2;   // ~49.1 MB
    // Old (R14) layout
    const size_t needA = 64 + 65536 + 2 * (size_t)DIM * DIM * 2 + 2 * DIM * 2
                       + 4 * (size_t)NTOK * DIM * 2;                  // ~33.1 MB
    const size_t needB = 64 + 2 * (size_t)NTOK * DIM * 2;             // 16.03 MB

    detect_kernel<<<dim3(1), dim3(64), 0, stream>>>((const ushort_t*)emb, flag);

    if (ws_size >= needC) {
        float*    lsum4 = (float*)(W + 64);                          // 128 KB
        ushort_t* Wqkb  = (ushort_t*)(W + 64 + 4 * (size_t)NTOK * 4);
        ushort_t* Wvb   = Wqkb + (size_t)DIM * DIM;
        ushort_t* bqkb  = Wvb + (size_t)DIM * DIM;
        ushort_t* bvb   = bqkb + DIM;
        ushort_t* embT  = bvb + DIM;                                 // 8 MB
        ushort_t* Qws   = embT + (size_t)DIM * NTOK;                 // 8 MB
        ushort_t* P4    = Qws + (size_t)DIM * NTOK;                  // 4 x 8 MB

        prep_kernel<<<dim3(128), dim3(256), 0, stream>>>(flag, Wqk, bqk, Wv, bv,
                                                         Wqkb, bqkb, Wvb, bvb);
        projqT_kernel<<<dim3(NTOK / 32), dim3(512), 0, stream>>>(flag, emb, Wqkb, bqkb,
                                                                 Qws, embT);
        attn128_kernel<<<dim3(256), dim3(512), 0, stream>>>(Qws, embT, P4, lsum4);
        finalize4_kernel<<<dim3(NTOK / 32), dim3(512), 0, stream>>>(flag, P4, lsum4,
                                                                    Wvb, bvb, d_out);
    } else if (ws_size >= needA) {
        float*    lsumA = (float*)(W + 64);                          // 64 KB
        ushort_t* Wqkb  = (ushort_t*)(W + 64 + 65536);
        ushort_t* Wvb   = Wqkb + (size_t)DIM * DIM;
        ushort_t* bqkb  = Wvb + (size_t)DIM * DIM;
        ushort_t* bvb   = bqkb + DIM;
        ushort_t* embT  = bvb + DIM;
        ushort_t* Qws   = embT + (size_t)DIM * NTOK;
        ushort_t* P0    = Qws + (size_t)DIM * NTOK;
        ushort_t* P1    = P0 + (size_t)NTOK * DIM;

        prep_kernel<<<dim3(128), dim3(256), 0, stream>>>(flag, Wqk, bqk, Wv, bv,
                                                         Wqkb, bqkb, Wvb, bvb);
        projq_kernel<<<dim3(NTOK / 32), dim3(512), 0, stream>>>(flag, emb, Wqkb, bqkb, Qws);
        // transpose path for embT (attn64 needs it)
        transpose_kernel<<<dim3(128, 8), dim3(256), 0, stream>>>(flag, emb, embT);
        attn64_kernel<<<dim3(256), dim3(1024), 0, stream>>>(Qws, embT, P0, P1, lsumA);
        finalize_kernel<<<dim3(NTOK / 64), dim3(512), 0, stream>>>(flag, P0, P1, lsumA,
                                                                   Wvb, bvb, d_out);
    } else if (ws_size >= needB) {
        ushort_t* embT2 = (ushort_t*)(W + 64);
        ushort_t* Qws2  = embT2 + (size_t)DIM * NTOK;
        transpose_kernel<<<dim3(128, 8), dim3(256), 0, stream>>>(flag, emb, embT2);
        projq_kernel<<<dim3(NTOK / 32), dim3(512), 0, stream>>>(flag, emb, Wqk, bqk, Qws2);
        attn_fused_kernel<1><<<dim3(NTOK / 32), dim3(1024), 0, stream>>>(
            flag, Qws2, embT2, Wv, bv, d_out);
    } else {
        ushort_t* Qsm = (ushort_t*)(W + 64);
        projq_kernel<<<dim3(NTOK / 32), dim3(512), 0, stream>>>(flag, emb, Wqk, bqk, Qsm);
        attn_fused_kernel<0><<<dim3(NTOK / 32), dim3(1024), 0, stream>>>(
            flag, Qsm, emb, Wv, bv, d_out);
    }
}